// Round 6
// baseline (425.351 us; speedup 1.0000x reference)
//
#include <hip/hip_runtime.h>
#include <hip/hip_bf16.h>
#include <hip/hip_fp16.h>
#include <cstdint>
#include <cstddef>
#include <cmath>

#define F_IN 256
#define HDIM 128
#define CCLS 40
#define NBMAX 1024   // max buckets (n<=65536); n=50000 -> 782
#define EPB_H 16384  // edges per hist block

typedef short bf16x8 __attribute__((ext_vector_type(8)));
typedef float f32x4 __attribute__((ext_vector_type(4)));

__device__ inline unsigned pkbf(float a, float b) {
  __hip_bfloat162 h = __float22bfloat162_rn(make_float2(a, b));
  unsigned u;
  __builtin_memcpy(&u, &h, 4);
  return u;
}
__device__ inline unsigned short bfr(float f) {
  __hip_bfloat16 h = __float2bfloat16(f);
  unsigned short u;
  __builtin_memcpy(&u, &h, 2);
  return u;
}
__device__ inline float f16tof(unsigned short hb) {
  __half hv;
  __builtin_memcpy(&hv, &hb, 2);
  return __half2float(hv);
}
__device__ inline unsigned short ftof16(float f) {
  __half hv = __float2half(f);
  unsigned short u;
  __builtin_memcpy(&u, &hv, 2);
  return u;
}

// ---- prep: W1T/W2T transpose (192) | Wc fold (2) | hist per-node + per-bucket (hb) ----
__global__ __launch_bounds__(256) void prep_kernel(const float* __restrict__ W1,
                                                   const float* __restrict__ W2,
                                                   unsigned short* __restrict__ W1T,
                                                   unsigned short* __restrict__ W2T,
                                                   const float* __restrict__ We,
                                                   const float* __restrict__ be,
                                                   const float* __restrict__ Wf,
                                                   const float* __restrict__ bf,
                                                   float* __restrict__ Wc,
                                                   float* __restrict__ bc,
                                                   const int* __restrict__ dst,
                                                   int* __restrict__ ncnt,
                                                   int* __restrict__ gcount,
                                                   int e, int nb) {
  const int b = blockIdx.x;
  const int t = threadIdx.x;
  if (b < 192) {                        // ---- W transpose + bf16
    int idx = b * 256 + t;
    if (idx < 128 * 256) {
      int nr = idx >> 8, k = idx & 255;
      W1T[idx] = bfr(W1[k * 128 + nr]);
    } else {
      int i2 = idx - 128 * 256;
      if (i2 < 128 * 128) {
        int nr = i2 >> 7, k = i2 & 127;
        W2T[i2] = bfr(W2[k * 128 + nr]);
      }
    }
  } else if (b < 194) {                 // ---- fold Wc = We @ Wf_top, bc (2 blocks)
    int part = b - 192;
    int lo = part * 800, hi = lo + 800;
    for (int i = lo + t; i < hi; i += 256) {
      int c = i / CCLS, j = i % CCLS;
      float s = 0.f;
      for (int f = 0; f < HDIM; ++f) s += We[c * HDIM + f] * Wf[f * CCLS + j];
      Wc[i] = s;
    }
    if (part == 0 && t < CCLS) {
      float s = bf[t];
      for (int f = 0; f < HDIM; ++f) s += be[f] * Wf[f * CCLS + t];
      bc[t] = s;
    }
  } else {                              // ---- histogram: node (global) + bucket (LDS-staged)
    __shared__ int h[NBMAX];
    for (int i = t; i < nb; i += 256) h[i] = 0;
    __syncthreads();
    int b4 = (b - 194) * (EPB_H / 4);
#pragma unroll
    for (int k = 0; k < EPB_H / 1024; ++k) {
      int gi = b4 + k * 256 + t;
      int e0 = gi * 4;
      int4 d = make_int4(-1, -1, -1, -1);
      if (e0 + 3 < e) d = ((const int4*)dst)[gi];
      else if (e0 < e) {
        d.x = dst[e0];
        if (e0 + 1 < e) d.y = dst[e0 + 1];
        if (e0 + 2 < e) d.z = dst[e0 + 2];
      }
      if (d.x >= 0) { atomicAdd(&h[d.x >> 6], 1); atomicAdd(&ncnt[d.x], 1); }
      if (d.y >= 0) { atomicAdd(&h[d.y >> 6], 1); atomicAdd(&ncnt[d.y], 1); }
      if (d.z >= 0) { atomicAdd(&h[d.z >> 6], 1); atomicAdd(&ncnt[d.z], 1); }
      if (d.w >= 0) { atomicAdd(&h[d.w >> 6], 1); atomicAdd(&ncnt[d.w], 1); }
    }
    __syncthreads();
    for (int i = t; i < nb; i += 256)
      if (h[i]) atomicAdd(&gcount[i], h[i]);
  }
}

// ---------------- row_scan: bucket base + 64-lane node scan -> row_off, cur ----------------
__global__ __launch_bounds__(256) void row_scan(const int* __restrict__ gcount,
                                                const int* __restrict__ ncnt,
                                                int* __restrict__ row_off,
                                                int* __restrict__ cur,
                                                int n, int nb, int e) {
  __shared__ int sred[4];
  const int t = threadIdx.x;
  const int b = blockIdx.x;
  int partial = 0;
  for (int i = t; i < b; i += 256) partial += gcount[i];
#pragma unroll
  for (int off = 32; off; off >>= 1) partial += __shfl_xor(partial, off, 64);
  if ((t & 63) == 0) sred[t >> 6] = partial;
  __syncthreads();
  const int e0 = sred[0] + sred[1] + sred[2] + sred[3];
  if (t < 64) {
    int node = b * 64 + t;
    int c = (node < n) ? ncnt[node] : 0;
    int x = c;
#pragma unroll
    for (int off = 1; off < 64; off <<= 1) {
      int y = __shfl_up(x, off, 64);
      if (t >= off) x += y;
    }
    int base = e0 + x - c;               // exclusive
    if (node < n) { row_off[node] = base; cur[node] = base; }
  }
  if (b == nb - 1 && t == 0) row_off[n] = e;
}

// ---------------- merged: direct counting-sort scatter (blocks < nsb) | gemm1 (rest) ----
// scatter: per edge, pos = atomicAdd(cur[dst]); write final packed 4B record.
// No LDS, no multisplit, no bucket_sort pass. gemm1 fully independent.
#define EPB 8192
__global__ __launch_bounds__(256) void scatter_gemm1(const int* __restrict__ src,
                                                     const int* __restrict__ dst,
                                                     const float* __restrict__ w,
                                                     int* __restrict__ cur,
                                                     unsigned* __restrict__ ews2,
                                                     const float* __restrict__ X,
                                                     const unsigned short* __restrict__ WT,
                                                     unsigned short* __restrict__ C,
                                                     int e, int nsb, int M) {
  __shared__ unsigned short As[64][264];   // gemm1 A-tile; scatter blocks don't touch it
  const int t = threadIdx.x;
  if ((int)blockIdx.x < nsb) {
    // ================= lean scatter =================
    const int b4 = blockIdx.x * 2048;
#pragma unroll
    for (int k = 0; k < 8; ++k) {
      int gi = b4 + k * 256 + t;
      int e0 = gi * 4;
      if (e0 >= e) continue;
      int4 d = make_int4(-1, -1, -1, -1);
      int4 s4 = make_int4(0, 0, 0, 0);
      float4 w4 = make_float4(0.f, 0.f, 0.f, 0.f);
      if (e0 + 3 < e) {
        d = ((const int4*)dst)[gi];
        s4 = ((const int4*)src)[gi];
        w4 = ((const float4*)w)[gi];
      } else {
        d.x = dst[e0]; s4.x = src[e0]; w4.x = w[e0];
        if (e0 + 1 < e) { d.y = dst[e0 + 1]; s4.y = src[e0 + 1]; w4.y = w[e0 + 1]; }
        if (e0 + 2 < e) { d.z = dst[e0 + 2]; s4.z = src[e0 + 2]; w4.z = w[e0 + 2]; }
      }
      if (d.x >= 0) { int p = atomicAdd(&cur[d.x], 1);
        ews2[p] = ((unsigned)s4.x & 0xFFFFu) | ((unsigned)ftof16(w4.x) << 16); }
      if (d.y >= 0) { int p = atomicAdd(&cur[d.y], 1);
        ews2[p] = ((unsigned)s4.y & 0xFFFFu) | ((unsigned)ftof16(w4.y) << 16); }
      if (d.z >= 0) { int p = atomicAdd(&cur[d.z], 1);
        ews2[p] = ((unsigned)s4.z & 0xFFFFu) | ((unsigned)ftof16(w4.z) << 16); }
      if (d.w >= 0) { int p = atomicAdd(&cur[d.w], 1);
        ews2[p] = ((unsigned)s4.w & 0xFFFFu) | ((unsigned)ftof16(w4.w) << 16); }
    }
  } else {
    // ================= gemm1: fused norm + MFMA =================
    const int w8 = t >> 6, l = t & 63;
    const int bm0 = (blockIdx.x - nsb) * 64;

    // phase 1: each wave normalizes its own 16 rows into LDS
    for (int rr = 0; rr < 16; ++rr) {
      int row = w8 * 16 + rr;
      int grow = bm0 + row;
      const float* p = X + (size_t)(grow < M ? grow : (M - 1)) * F_IN + l * 4;
      float4 v = *(const float4*)p;
      float s = v.x * v.x + v.y * v.y + v.z * v.z + v.w * v.w;
#pragma unroll
      for (int off = 32; off; off >>= 1) s += __shfl_xor(s, off, 64);
      float inv = 1.0f / fmaxf(sqrtf(s), 1e-12f);
      *(uint2*)&As[row][l * 4] =
          make_uint2(pkbf(v.x * inv, v.y * inv), pkbf(v.z * inv, v.w * inv));
    }

    // phase 2: MFMA from LDS A (no barrier: wave reads only rows it wrote)
    const int ln = l & 15, quad = l >> 4;
    const int m0 = bm0 + w8 * 16;
    f32x4 acc[8];
#pragma unroll
    for (int i = 0; i < 8; ++i) acc[i] = (f32x4){0.f, 0.f, 0.f, 0.f};

#pragma unroll
    for (int k0 = 0; k0 < F_IN; k0 += 32) {
      bf16x8 af = *(const bf16x8*)&As[w8 * 16 + ln][k0 + quad * 8];
#pragma unroll
      for (int ti = 0; ti < 8; ++ti) {
        bf16x8 bfv = *(const bf16x8*)(WT + (size_t)(ti * 16 + ln) * F_IN + k0 + quad * 8);
        acc[ti] = __builtin_amdgcn_mfma_f32_16x16x32_bf16(af, bfv, acc[ti], 0, 0, 0);
      }
    }

#pragma unroll
    for (int r = 0; r < 4; ++r) {
      int grow = m0 + quad * 4 + r;
      if (grow < M) {
        unsigned short* cp = C + (size_t)grow * HDIM + ln;
#pragma unroll
        for (int ti = 0; ti < 8; ++ti) cp[ti * 16] = bfr(acc[ti][r]);
      }
    }
  }
}

// decode + gather + fma for a pair of packed edge records (half selects)
#define SPMM_PAIR(ua, ub)                                                      \
  {                                                                            \
    unsigned u = half ? (ub) : (ua);                                           \
    float wt = f16tof((unsigned short)(u >> 16));                              \
    const uint2 xv = *(const uint2*)(xin + (size_t)(u & 0xFFFFu) * HDIM + fo); \
    acc.x = fmaf(wt, __uint_as_float(xv.x << 16), acc.x);                      \
    acc.y = fmaf(wt, __uint_as_float(xv.x & 0xFFFF0000u), acc.y);              \
    acc.z = fmaf(wt, __uint_as_float(xv.y << 16), acc.z);                      \
    acc.w = fmaf(wt, __uint_as_float(xv.y & 0xFFFF0000u), acc.w);              \
  }

// ---------------- SPMM v2 (proven): full-width, wave/node, 16-edge unroll ----------------
template <int OUT_BF16>
__global__ __launch_bounds__(256) void spmm_bf16(const unsigned short* __restrict__ xin,
                                                 const unsigned* __restrict__ ews,
                                                 const int* __restrict__ row_off,
                                                 const float* __restrict__ bias,
                                                 void* __restrict__ outp, int n,
                                                 int do_relu) {
  const int t = threadIdx.x;
  const int l = t & 63;
  const int node = blockIdx.x * 4 + (t >> 6);
  if (node >= n) return;
  const int ue0 = __builtin_amdgcn_readfirstlane(row_off[node]);
  const int ue1 = __builtin_amdgcn_readfirstlane(row_off[node + 1]);
  const int cnt = ue1 - ue0;
  const unsigned* ep = ews + ue0;              // wave-uniform -> scalar loads
  const int fo = (l & 31) * 4;
  const int half = l >> 5;
  float4 acc = make_float4(0.f, 0.f, 0.f, 0.f);

  int k = 0;
  for (; k + 16 <= cnt; k += 16) {             // 8 independent gathers in flight
    unsigned a0 = ep[k + 0], a1 = ep[k + 1], a2 = ep[k + 2], a3 = ep[k + 3];
    unsigned a4 = ep[k + 4], a5 = ep[k + 5], a6 = ep[k + 6], a7 = ep[k + 7];
    unsigned a8 = ep[k + 8], a9 = ep[k + 9], a10 = ep[k + 10], a11 = ep[k + 11];
    unsigned a12 = ep[k + 12], a13 = ep[k + 13], a14 = ep[k + 14], a15 = ep[k + 15];
    SPMM_PAIR(a0, a1);
    SPMM_PAIR(a2, a3);
    SPMM_PAIR(a4, a5);
    SPMM_PAIR(a6, a7);
    SPMM_PAIR(a8, a9);
    SPMM_PAIR(a10, a11);
    SPMM_PAIR(a12, a13);
    SPMM_PAIR(a14, a15);
  }
  for (; k + 8 <= cnt; k += 8) {
    unsigned a0 = ep[k + 0], a1 = ep[k + 1], a2 = ep[k + 2], a3 = ep[k + 3];
    unsigned a4 = ep[k + 4], a5 = ep[k + 5], a6 = ep[k + 6], a7 = ep[k + 7];
    SPMM_PAIR(a0, a1);
    SPMM_PAIR(a2, a3);
    SPMM_PAIR(a4, a5);
    SPMM_PAIR(a6, a7);
  }
  for (; k < cnt; k += 2) {
    unsigned a0 = ep[k];
    unsigned a1 = (k + 1 < cnt) ? ep[k + 1] : 0u;  // w=+0, src=0 -> safe
    SPMM_PAIR(a0, a1);
  }

  acc.x += __shfl_xor(acc.x, 32, 64);
  acc.y += __shfl_xor(acc.y, 32, 64);
  acc.z += __shfl_xor(acc.z, 32, 64);
  acc.w += __shfl_xor(acc.w, 32, 64);
  if (l < 32) {
    float4 bv = *(const float4*)(bias + fo);
    float4 r = make_float4(acc.x + bv.x, acc.y + bv.y, acc.z + bv.z, acc.w + bv.w);
    if (do_relu) {
      r.x = fmaxf(r.x, 0.f); r.y = fmaxf(r.y, 0.f);
      r.z = fmaxf(r.z, 0.f); r.w = fmaxf(r.w, 0.f);
    }
    if (OUT_BF16) {
      uint2 o = make_uint2(pkbf(r.x, r.y), pkbf(r.z, r.w));
      *(uint2*)((unsigned short*)outp + (size_t)node * HDIM + fo) = o;
    } else {
      *(float4*)((float*)outp + (size_t)node * HDIM + fo) = r;
    }
  }
}

// ---------------- MFMA GEMM: C[M][128] = A[M][K](bf16) @ WT[128][K](bf16) ----------------
template <int K>
__global__ __launch_bounds__(256) void gemm_mfma(const unsigned short* __restrict__ A,
                                                 const unsigned short* __restrict__ WT,
                                                 unsigned short* __restrict__ C, int M) {
  const int t = threadIdx.x;
  const int w = t >> 6, l = t & 63;
  const int ln = l & 15, quad = l >> 4;
  const int m0 = blockIdx.x * 64 + w * 16;
  const int arow = m0 + ln;
  const unsigned short* aptr = A + (size_t)(arow < M ? arow : (M - 1)) * K + quad * 8;

  f32x4 acc[8];
#pragma unroll
  for (int i = 0; i < 8; ++i) acc[i] = (f32x4){0.f, 0.f, 0.f, 0.f};

#pragma unroll
  for (int k0 = 0; k0 < K; k0 += 32) {
    bf16x8 af = *(const bf16x8*)(aptr + k0);
#pragma unroll
    for (int ti = 0; ti < 8; ++ti) {
      bf16x8 bfv = *(const bf16x8*)(WT + (size_t)(ti * 16 + ln) * K + k0 + quad * 8);
      acc[ti] = __builtin_amdgcn_mfma_f32_16x16x32_bf16(af, bfv, acc[ti], 0, 0, 0);
    }
  }

#pragma unroll
  for (int r = 0; r < 4; ++r) {
    int grow = m0 + quad * 4 + r;
    if (grow < M) {
      unsigned short* cp = C + (size_t)grow * HDIM + ln;
#pragma unroll
      for (int ti = 0; ti < 8; ++ti) cp[ti * 16] = bfr(acc[ti][r]);
    }
  }
}

// ---------------- head: 256-thread blocks (4 waves share one LDS fill) ----------------
__global__ __launch_bounds__(256) void head_kernel(const float* __restrict__ y,
                                                   const float* __restrict__ h2,
                                                   const float* __restrict__ Wc,
                                                   const float* __restrict__ bc,
                                                   const float* __restrict__ Wf,
                                                   float* __restrict__ out, int n) {
  __shared__ float sW[169 * CCLS];
  const int t = threadIdx.x;
  for (int i = t; i < 400; i += 256) ((float4*)sW)[i] = ((const float4*)Wc)[i];
  for (int i = t; i < 1280; i += 256)
    ((float4*)(sW + CCLS * CCLS))[i] = ((const float4*)(Wf + HDIM * CCLS))[i];
  if (t < 10) ((float4*)(sW + 168 * CCLS))[t] = ((const float4*)bc)[t];
  __syncthreads();

  const int node = blockIdx.x * 256 + t;
  const int nc = node < n ? node : n - 1;
  const float* zy = y + (size_t)nc * CCLS;
  const float* zh = h2 + (size_t)nc * HDIM;

  float acc[40];
#pragma unroll
  for (int cq = 0; cq < 10; ++cq) {
    float4 b4 = *(const float4*)&sW[168 * CCLS + cq * 4];
    acc[cq * 4 + 0] = b4.x; acc[cq * 4 + 1] = b4.y;
    acc[cq * 4 + 2] = b4.z; acc[cq * 4 + 3] = b4.w;
  }

#pragma unroll 2
  for (int kc = 0; kc < 10; ++kc) {      // y part: K = 40
    float4 zv = *(const float4*)(zy + kc * 4);
    float zj[4] = {zv.x, zv.y, zv.z, zv.w};
#pragma unroll
    for (int j = 0; j < 4; ++j) {
      const float* wr = sW + (kc * 4 + j) * CCLS;
#pragma unroll
      for (int cq = 0; cq < 10; ++cq) {
        float4 w4 = *(const float4*)(wr + cq * 4);
        acc[cq * 4 + 0] = fmaf(zj[j], w4.x, acc[cq * 4 + 0]);
        acc[cq * 4 + 1] = fmaf(zj[j], w4.y, acc[cq * 4 + 1]);
        acc[cq * 4 + 2] = fmaf(zj[j], w4.z, acc[cq * 4 + 2]);
        acc[cq * 4 + 3] = fmaf(zj[j], w4.w, acc[cq * 4 + 3]);
      }
    }
  }
#pragma unroll 2
  for (int kc = 0; kc < 32; ++kc) {      // h2 part: K = 128
    float4 zv = *(const float4*)(zh + kc * 4);
    float zj[4] = {zv.x, zv.y, zv.z, zv.w};
#pragma unroll
    for (int j = 0; j < 4; ++j) {
      const float* wr = sW + (40 + kc * 4 + j) * CCLS;
#pragma unroll
      for (int cq = 0; cq < 10; ++cq) {
        float4 w4 = *(const float4*)(wr + cq * 4);
        acc[cq * 4 + 0] = fmaf(zj[j], w4.x, acc[cq * 4 + 0]);
        acc[cq * 4 + 1] = fmaf(zj[j], w4.y, acc[cq * 4 + 1]);
        acc[cq * 4 + 2] = fmaf(zj[j], w4.z, acc[cq * 4 + 2]);
        acc[cq * 4 + 3] = fmaf(zj[j], w4.w, acc[cq * 4 + 3]);
      }
    }
  }

  // in-register softmax over 40 logits
  float m = acc[0];
#pragma unroll
  for (int c = 1; c < 40; ++c) m = fmaxf(m, acc[c]);
  float sum = 0.f;
#pragma unroll
  for (int c = 0; c < 40; ++c) { acc[c] = __expf(acc[c] - m); sum += acc[c]; }
  float inv = 1.0f / sum;
  if (node < n) {
    float* op = out + (size_t)node * CCLS;
#pragma unroll
    for (int cq = 0; cq < 10; ++cq) {
      float4 o = make_float4(acc[cq * 4 + 0] * inv, acc[cq * 4 + 1] * inv,
                             acc[cq * 4 + 2] * inv, acc[cq * 4 + 3] * inv);
      *(float4*)(op + cq * 4) = o;
    }
  }
}

extern "C" void kernel_launch(void* const* d_in, const int* in_sizes, int n_in,
                              void* d_out, int out_size, void* d_ws, size_t ws_size,
                              hipStream_t stream) {
  (void)n_in; (void)out_size; (void)ws_size;
  const float* features = (const float*)d_in[0];
  const int*   src      = (const int*)d_in[1];
  const int*   dst      = (const int*)d_in[2];
  const float* ew       = (const float*)d_in[3];
  const float* y        = (const float*)d_in[4];
  const float* W1       = (const float*)d_in[5];
  const float* b1       = (const float*)d_in[6];
  const float* W2       = (const float*)d_in[7];
  const float* b2       = (const float*)d_in[8];
  const float* We       = (const float*)d_in[9];
  const float* be       = (const float*)d_in[10];
  const float* Wf       = (const float*)d_in[11];
  const float* bf       = (const float*)d_in[12];
  float* out = (float*)d_out;

  const int n = in_sizes[0] / F_IN;   // 50000
  const int e = in_sizes[1];          // 1600000
  const int nb = (n + 63) >> 6;       // 782 buckets

  char* w = (char*)d_ws;
  auto take = [&](size_t bytes) {
    char* p = w;
    w += (bytes + 255) & ~(size_t)255;
    return p;
  };
  int*   gz       = (int*)take((size_t)(n + nb) * 4);  // ncnt | gcount (one memset)
  int*   ncnt     = gz;
  int*   gcount   = gz + n;
  int*   row_off  = (int*)take((size_t)(n + 1) * 4);
  int*   cur      = (int*)take((size_t)n * 4);
  unsigned* ews2  = (unsigned*)take((size_t)(e + 16) * 4);
  unsigned short* bufH1  = (unsigned short*)take((size_t)n * HDIM * 2);
  unsigned short* bufH2  = (unsigned short*)take((size_t)n * HDIM * 2);
  float* bufS     = (float*)take((size_t)n * HDIM * 4);
  unsigned short* W1T = (unsigned short*)take((size_t)HDIM * F_IN * 2);
  unsigned short* W2T = (unsigned short*)take((size_t)HDIM * HDIM * 2);
  float* Wc       = (float*)take(CCLS * CCLS * 4);
  float* bc       = (float*)take(CCLS * 4);

  const int hb = (e + EPB_H - 1) / EPB_H;
  const int nsb = (e + EPB - 1) / EPB;               // scatter blocks (196)
  const int ngb = (n + 63) / 64;                     // gemm1 blocks (782)
  hipMemsetAsync(gz, 0, (size_t)(n + nb) * 4, stream);
  prep_kernel<<<194 + hb, 256, 0, stream>>>(W1, W2, W1T, W2T, We, be, Wf, bf, Wc, bc,
                                            dst, ncnt, gcount, e, nb);
  row_scan<<<nb, 256, 0, stream>>>(gcount, ncnt, row_off, cur, n, nb, e);
  scatter_gemm1<<<nsb + ngb, 256, 0, stream>>>(src, dst, ew, cur, ews2,
                                               features, W1T, bufH1, e, nsb, n);

  spmm_bf16<1><<<(n + 3) / 4, 256, 0, stream>>>(bufH1, ews2, row_off, b1, bufH2, n, 1);
  gemm_mfma<HDIM><<<(n + 63) / 64, 256, 0, stream>>>(bufH2, W2T, bufH1, n);
  spmm_bf16<0><<<(n + 3) / 4, 256, 0, stream>>>(bufH1, ews2, row_off, b2, bufS, n, 0);
  head_kernel<<<(n + 255) / 256, 256, 0, stream>>>(y, bufS, Wc, bc, Wf, out, n);
}

// Round 7
// 367.348 us; speedup vs baseline: 1.1579x; 1.1579x over previous
//
#include <hip/hip_runtime.h>
#include <hip/hip_bf16.h>
#include <hip/hip_fp16.h>
#include <cstdint>
#include <cstddef>
#include <cmath>

#define F_IN 256
#define HDIM 128
#define CCLS 40
#define NBMAX 1024   // max buckets (n<=65536); n=50000 -> 782
#define EPB_H 16384  // edges per hist block
#define EPB 8192     // edges per scatter block

typedef short bf16x8 __attribute__((ext_vector_type(8)));
typedef float f32x4 __attribute__((ext_vector_type(4)));

__device__ inline unsigned pkbf(float a, float b) {
  __hip_bfloat162 h = __float22bfloat162_rn(make_float2(a, b));
  unsigned u;
  __builtin_memcpy(&u, &h, 4);
  return u;
}
__device__ inline unsigned short bfr(float f) {
  __hip_bfloat16 h = __float2bfloat16(f);
  unsigned short u;
  __builtin_memcpy(&u, &h, 2);
  return u;
}
__device__ inline float f16tof(unsigned short hb) {
  __half hv;
  __builtin_memcpy(&hv, &hb, 2);
  return __half2float(hv);
}
__device__ inline unsigned short ftof16(float f) {
  __half hv = __float2half(f);
  unsigned short u;
  __builtin_memcpy(&u, &hv, 2);
  return u;
}

// ---- gemm1 fused body: normalize 16 rows/wave into LDS, MFMA C[64][128] ----
__device__ inline void gemm1_body(char* smem, int bm0, const float* __restrict__ X,
                                  const unsigned short* __restrict__ WT,
                                  unsigned short* __restrict__ C, int M, int t) {
  unsigned short (*As)[264] = (unsigned short(*)[264])smem;
  const int w8 = t >> 6, l = t & 63;

  for (int rr = 0; rr < 16; ++rr) {
    int row = w8 * 16 + rr;
    int grow = bm0 + row;
    const float* p = X + (size_t)(grow < M ? grow : (M - 1)) * F_IN + l * 4;
    float4 v = *(const float4*)p;
    float s = v.x * v.x + v.y * v.y + v.z * v.z + v.w * v.w;
#pragma unroll
    for (int off = 32; off; off >>= 1) s += __shfl_xor(s, off, 64);
    float inv = 1.0f / fmaxf(sqrtf(s), 1e-12f);
    *(uint2*)&As[row][l * 4] =
        make_uint2(pkbf(v.x * inv, v.y * inv), pkbf(v.z * inv, v.w * inv));
  }

  const int ln = l & 15, quad = l >> 4;
  const int m0 = bm0 + w8 * 16;
  f32x4 acc[8];
#pragma unroll
  for (int i = 0; i < 8; ++i) acc[i] = (f32x4){0.f, 0.f, 0.f, 0.f};

#pragma unroll
  for (int k0 = 0; k0 < F_IN; k0 += 32) {
    bf16x8 af = *(const bf16x8*)&As[w8 * 16 + ln][k0 + quad * 8];
#pragma unroll
    for (int ti = 0; ti < 8; ++ti) {
      bf16x8 bfv = *(const bf16x8*)(WT + (size_t)(ti * 16 + ln) * F_IN + k0 + quad * 8);
      acc[ti] = __builtin_amdgcn_mfma_f32_16x16x32_bf16(af, bfv, acc[ti], 0, 0, 0);
    }
  }

#pragma unroll
  for (int r = 0; r < 4; ++r) {
    int grow = m0 + quad * 4 + r;
    if (grow < M) {
      unsigned short* cp = C + (size_t)grow * HDIM + ln;
#pragma unroll
      for (int ti = 0; ti < 8; ++ti) cp[ti * 16] = bfr(acc[ti][r]);
    }
  }
}

// ---- prep: W1T transpose (128 blocks) | bucket hist (hb blocks) ----
__global__ __launch_bounds__(256) void prep_kernel(const float* __restrict__ W1,
                                                   unsigned short* __restrict__ W1T,
                                                   const int* __restrict__ dst,
                                                   int* __restrict__ gcount,
                                                   int e, int nb) {
  const int b = blockIdx.x;
  const int t = threadIdx.x;
  if (b < 128) {                        // W1T transpose + bf16 (128x256)
    int idx = b * 256 + t;
    int nr = idx >> 8, k = idx & 255;
    W1T[idx] = bfr(W1[k * 128 + nr]);
  } else {                              // bucket histogram, 16384 edges/block
    __shared__ int h[NBMAX];
    for (int i = t; i < nb; i += 256) h[i] = 0;
    __syncthreads();
    int b4 = (b - 128) * (EPB_H / 4);
#pragma unroll
    for (int k = 0; k < EPB_H / 1024; ++k) {
      int gi = b4 + k * 256 + t;
      int e0 = gi * 4;
      int4 d = make_int4(-1, -1, -1, -1);
      if (e0 + 3 < e) d = ((const int4*)dst)[gi];
      else if (e0 < e) {
        d.x = dst[e0];
        if (e0 + 1 < e) d.y = dst[e0 + 1];
        if (e0 + 2 < e) d.z = dst[e0 + 2];
      }
      if (d.x >= 0) atomicAdd(&h[d.x >> 6], 1);
      if (d.y >= 0) atomicAdd(&h[d.y >> 6], 1);
      if (d.z >= 0) atomicAdd(&h[d.z >> 6], 1);
      if (d.w >= 0) atomicAdd(&h[d.w >> 6], 1);
    }
    __syncthreads();
    for (int i = t; i < nb; i += 256)
      if (h[i]) atomicAdd(&gcount[i], h[i]);
  }
}

// ---- dispatch 2: multisplit scatter (196 blocks) | gemm1 part A ----
__global__ __launch_bounds__(256) void scatter_gemm1(const int* __restrict__ src,
                                                     const int* __restrict__ dst,
                                                     const float* __restrict__ w,
                                                     const int* __restrict__ gcount,
                                                     int* __restrict__ gcursor,
                                                     uint2* __restrict__ ews,
                                                     const float* __restrict__ X,
                                                     const unsigned short* __restrict__ WT,
                                                     unsigned short* __restrict__ C,
                                                     int e, int nb, int nsb, int M) {
  __shared__ char smem[64 * 264 * 2];   // union: gemm1 A-tile | scatter tables
  const int t = threadIdx.x;
  if ((int)blockIdx.x < nsb) {
    // ================= multisplit scatter =================
    int* hist = (int*)smem;
    int* sb   = hist + NBMAX;
    int* lcur = sb + NBMAX;
    int* part = lcur + NBMAX;
    for (int i = t; i < nb; i += 256) { hist[i] = 0; lcur[i] = 0; }
    __syncthreads();
    const int b4 = blockIdx.x * 2048;
    int4 dv[8];
#pragma unroll
    for (int k = 0; k < 8; ++k) {
      int gi = b4 + k * 256 + t;
      int e0 = gi * 4;
      int4 d = make_int4(-1, -1, -1, -1);
      if (e0 + 3 < e) d = ((const int4*)dst)[gi];
      else if (e0 < e) {
        d.x = dst[e0];
        if (e0 + 1 < e) d.y = dst[e0 + 1];
        if (e0 + 2 < e) d.z = dst[e0 + 2];
      }
      dv[k] = d;
      if (d.x >= 0) atomicAdd(&hist[d.x >> 6], 1);
      if (d.y >= 0) atomicAdd(&hist[d.y >> 6], 1);
      if (d.z >= 0) atomicAdd(&hist[d.z >> 6], 1);
      if (d.w >= 0) atomicAdd(&hist[d.w >> 6], 1);
    }
    __syncthreads();
    // in-block exclusive scan of gcount[0..nb) -> sb
    int v[4];
    int s = 0;
#pragma unroll
    for (int k = 0; k < 4; ++k) {
      int i = t * 4 + k;
      v[k] = (i < nb) ? gcount[i] : 0;
      s += v[k];
    }
    part[t] = s;
    __syncthreads();
    for (int off = 1; off < 256; off <<= 1) {
      int x = part[t];
      if (t >= off) x += part[t - off];
      __syncthreads();
      part[t] = x;
      __syncthreads();
    }
    int run = (t == 0) ? 0 : part[t - 1];
#pragma unroll
    for (int k = 0; k < 4; ++k) {
      int i = t * 4 + k;
      if (i < nb) sb[i] = run;
      run += v[k];
    }
    __syncthreads();
    for (int i = t; i < nb; i += 256) {
      int c = hist[i];
      sb[i] = sb[i] + (c ? atomicAdd(&gcursor[i], c) : 0);
    }
    __syncthreads();
#pragma unroll
    for (int k = 0; k < 8; ++k) {
      int gi = b4 + k * 256 + t;
      int e0 = gi * 4;
      if (e0 >= e) continue;
      int4 s4 = make_int4(0, 0, 0, 0);
      float4 w4 = make_float4(0.f, 0.f, 0.f, 0.f);
      if (e0 + 3 < e) { s4 = ((const int4*)src)[gi]; w4 = ((const float4*)w)[gi]; }
      else {
        s4.x = src[e0]; w4.x = w[e0];
        if (e0 + 1 < e) { s4.y = src[e0 + 1]; w4.y = w[e0 + 1]; }
        if (e0 + 2 < e) { s4.z = src[e0 + 2]; w4.z = w[e0 + 2]; }
      }
      int4 d = dv[k];
      if (d.x >= 0) { int bb = d.x >> 6; int r = atomicAdd(&lcur[bb], 1);
        ews[sb[bb] + r] = make_uint2(((unsigned)(d.x & 63) << 26) | (unsigned)s4.x, __float_as_uint(w4.x)); }
      if (d.y >= 0) { int bb = d.y >> 6; int r = atomicAdd(&lcur[bb], 1);
        ews[sb[bb] + r] = make_uint2(((unsigned)(d.y & 63) << 26) | (unsigned)s4.y, __float_as_uint(w4.y)); }
      if (d.z >= 0) { int bb = d.z >> 6; int r = atomicAdd(&lcur[bb], 1);
        ews[sb[bb] + r] = make_uint2(((unsigned)(d.z & 63) << 26) | (unsigned)s4.z, __float_as_uint(w4.z)); }
      if (d.w >= 0) { int bb = d.w >> 6; int r = atomicAdd(&lcur[bb], 1);
        ews[sb[bb] + r] = make_uint2(((unsigned)(d.w & 63) << 26) | (unsigned)s4.w, __float_as_uint(w4.w)); }
    }
  } else {
    gemm1_body(smem, (blockIdx.x - nsb) * 64, X, WT, C, M, t);
  }
}

// ---- dispatch 3: bucket_sort (nb blocks) | gemm1 part B | W2T transpose | Wc fold ----
__global__ __launch_bounds__(256) void sort_misc(const uint2* __restrict__ ews,
                                                 const int* __restrict__ gcount,
                                                 unsigned* __restrict__ ews2,
                                                 int* __restrict__ row_off,
                                                 const float* __restrict__ X,
                                                 const unsigned short* __restrict__ W1T,
                                                 unsigned short* __restrict__ C,
                                                 const float* __restrict__ W2,
                                                 unsigned short* __restrict__ W2T,
                                                 const float* __restrict__ We,
                                                 const float* __restrict__ be,
                                                 const float* __restrict__ Wf,
                                                 const float* __restrict__ bf,
                                                 float* __restrict__ Wc,
                                                 float* __restrict__ bc,
                                                 int n, int nb, int G1, int G2, int M) {
  __shared__ char smem[64 * 264 * 2];
  const int t = threadIdx.x;
  const int b = blockIdx.x;
  if (b < nb) {
    // ============ bucket_sort: per-wave counters + wave-parallel scan ============
    int* cnt  = (int*)smem;        // [4][64]
    int* cur  = cnt + 256;         // [64]
    int* sred = cur + 64;          // [4]
    int partial = 0;
    for (int i = t; i < b; i += 256) partial += gcount[i];
#pragma unroll
    for (int off = 32; off; off >>= 1) partial += __shfl_xor(partial, off, 64);
    if ((t & 63) == 0) sred[t >> 6] = partial;
    cnt[t] = 0;
    __syncthreads();
    const int e0 = sred[0] + sred[1] + sred[2] + sred[3];
    const int e1 = e0 + gcount[b];
    const int wv = t >> 6;
    for (int i = e0 + t; i < e1; i += 256)
      atomicAdd(&cnt[wv * 64 + ((unsigned)ews[i].x >> 26)], 1);
    __syncthreads();
    if (t < 64) {
      int tot = cnt[t] + cnt[64 + t] + cnt[128 + t] + cnt[192 + t];
      int x = tot;
#pragma unroll
      for (int off = 1; off < 64; off <<= 1) {
        int y = __shfl_up(x, off, 64);
        if (t >= off) x += y;
      }
      int excl = x - tot;
      cur[t] = excl;
      int node = b * 64 + t;
      if (node < n) row_off[node] = e0 + excl;
    }
    if (b == nb - 1 && t == 0) row_off[n] = e1;
    __syncthreads();
    for (int i = e0 + t; i < e1; i += 256) {
      uint2 p = ews[i];
      int d = (unsigned)p.x >> 26;
      int pos = e0 + atomicAdd(&cur[d], 1);
      ews2[pos] = (p.x & 0xFFFFu) | ((unsigned)ftof16(__uint_as_float(p.y)) << 16);
    }
  } else if (b < nb + G2) {
    gemm1_body(smem, (b - nb + G1) * 64, X, W1T, C, M, t);
  } else if (b < nb + G2 + 64) {
    // W2T transpose (128x128)
    int idx = (b - nb - G2) * 256 + t;
    int nr = idx >> 7, k = idx & 127;
    W2T[idx] = bfr(W2[k * 128 + nr]);
  } else {
    // Wc = We @ Wf_top fold + bc (2 blocks)
    int part = b - (nb + G2 + 64);
    int lo = part * 800, hi = lo + 800;
    for (int i = lo + t; i < hi; i += 256) {
      int c = i / CCLS, j = i % CCLS;
      float s = 0.f;
      for (int f = 0; f < HDIM; ++f) s += We[c * HDIM + f] * Wf[f * CCLS + j];
      Wc[i] = s;
    }
    if (part == 0 && t < CCLS) {
      float s = bf[t];
      for (int f = 0; f < HDIM; ++f) s += be[f] * Wf[f * CCLS + t];
      bc[t] = s;
    }
  }
}

// decode + gather + fma for a pair of packed edge records (half selects)
#define SPMM_PAIR(ua, ub)                                                      \
  {                                                                            \
    unsigned u = half ? (ub) : (ua);                                           \
    float wt = f16tof((unsigned short)(u >> 16));                              \
    const uint2 xv = *(const uint2*)(xin + (size_t)(u & 0xFFFFu) * HDIM + fo); \
    acc.x = fmaf(wt, __uint_as_float(xv.x << 16), acc.x);                      \
    acc.y = fmaf(wt, __uint_as_float(xv.x & 0xFFFF0000u), acc.y);              \
    acc.z = fmaf(wt, __uint_as_float(xv.y << 16), acc.z);                      \
    acc.w = fmaf(wt, __uint_as_float(xv.y & 0xFFFF0000u), acc.w);              \
  }

// ---------------- SPMM v2 (proven): full-width, wave/node, 16-edge unroll ----------------
template <int OUT_BF16>
__global__ __launch_bounds__(256) void spmm_bf16(const unsigned short* __restrict__ xin,
                                                 const unsigned* __restrict__ ews,
                                                 const int* __restrict__ row_off,
                                                 const float* __restrict__ bias,
                                                 void* __restrict__ outp, int n,
                                                 int do_relu) {
  const int t = threadIdx.x;
  const int l = t & 63;
  const int node = blockIdx.x * 4 + (t >> 6);
  if (node >= n) return;
  const int ue0 = __builtin_amdgcn_readfirstlane(row_off[node]);
  const int ue1 = __builtin_amdgcn_readfirstlane(row_off[node + 1]);
  const int cnt = ue1 - ue0;
  const unsigned* ep = ews + ue0;              // wave-uniform -> scalar loads
  const int fo = (l & 31) * 4;
  const int half = l >> 5;
  float4 acc = make_float4(0.f, 0.f, 0.f, 0.f);

  int k = 0;
  for (; k + 16 <= cnt; k += 16) {             // 8 independent gathers in flight
    unsigned a0 = ep[k + 0], a1 = ep[k + 1], a2 = ep[k + 2], a3 = ep[k + 3];
    unsigned a4 = ep[k + 4], a5 = ep[k + 5], a6 = ep[k + 6], a7 = ep[k + 7];
    unsigned a8 = ep[k + 8], a9 = ep[k + 9], a10 = ep[k + 10], a11 = ep[k + 11];
    unsigned a12 = ep[k + 12], a13 = ep[k + 13], a14 = ep[k + 14], a15 = ep[k + 15];
    SPMM_PAIR(a0, a1);
    SPMM_PAIR(a2, a3);
    SPMM_PAIR(a4, a5);
    SPMM_PAIR(a6, a7);
    SPMM_PAIR(a8, a9);
    SPMM_PAIR(a10, a11);
    SPMM_PAIR(a12, a13);
    SPMM_PAIR(a14, a15);
  }
  for (; k + 8 <= cnt; k += 8) {
    unsigned a0 = ep[k + 0], a1 = ep[k + 1], a2 = ep[k + 2], a3 = ep[k + 3];
    unsigned a4 = ep[k + 4], a5 = ep[k + 5], a6 = ep[k + 6], a7 = ep[k + 7];
    SPMM_PAIR(a0, a1);
    SPMM_PAIR(a2, a3);
    SPMM_PAIR(a4, a5);
    SPMM_PAIR(a6, a7);
  }
  for (; k < cnt; k += 2) {
    unsigned a0 = ep[k];
    unsigned a1 = (k + 1 < cnt) ? ep[k + 1] : 0u;  // w=+0, src=0 -> safe
    SPMM_PAIR(a0, a1);
  }

  acc.x += __shfl_xor(acc.x, 32, 64);
  acc.y += __shfl_xor(acc.y, 32, 64);
  acc.z += __shfl_xor(acc.z, 32, 64);
  acc.w += __shfl_xor(acc.w, 32, 64);
  if (l < 32) {
    float4 bv = *(const float4*)(bias + fo);
    float4 r = make_float4(acc.x + bv.x, acc.y + bv.y, acc.z + bv.z, acc.w + bv.w);
    if (do_relu) {
      r.x = fmaxf(r.x, 0.f); r.y = fmaxf(r.y, 0.f);
      r.z = fmaxf(r.z, 0.f); r.w = fmaxf(r.w, 0.f);
    }
    if (OUT_BF16) {
      uint2 o = make_uint2(pkbf(r.x, r.y), pkbf(r.z, r.w));
      *(uint2*)((unsigned short*)outp + (size_t)node * HDIM + fo) = o;
    } else {
      *(float4*)((float*)outp + (size_t)node * HDIM + fo) = r;
    }
  }
}

// ---------------- MFMA GEMM: C[M][128] = A[M][K](bf16) @ WT[128][K](bf16) ----------------
template <int K>
__global__ __launch_bounds__(256) void gemm_mfma(const unsigned short* __restrict__ A,
                                                 const unsigned short* __restrict__ WT,
                                                 unsigned short* __restrict__ C, int M) {
  const int t = threadIdx.x;
  const int w = t >> 6, l = t & 63;
  const int ln = l & 15, quad = l >> 4;
  const int m0 = blockIdx.x * 64 + w * 16;
  const int arow = m0 + ln;
  const unsigned short* aptr = A + (size_t)(arow < M ? arow : (M - 1)) * K + quad * 8;

  f32x4 acc[8];
#pragma unroll
  for (int i = 0; i < 8; ++i) acc[i] = (f32x4){0.f, 0.f, 0.f, 0.f};

#pragma unroll
  for (int k0 = 0; k0 < K; k0 += 32) {
    bf16x8 af = *(const bf16x8*)(aptr + k0);
#pragma unroll
    for (int ti = 0; ti < 8; ++ti) {
      bf16x8 bfv = *(const bf16x8*)(WT + (size_t)(ti * 16 + ln) * K + k0 + quad * 8);
      acc[ti] = __builtin_amdgcn_mfma_f32_16x16x32_bf16(af, bfv, acc[ti], 0, 0, 0);
    }
  }

#pragma unroll
  for (int r = 0; r < 4; ++r) {
    int grow = m0 + quad * 4 + r;
    if (grow < M) {
      unsigned short* cp = C + (size_t)grow * HDIM + ln;
#pragma unroll
      for (int ti = 0; ti < 8; ++ti) cp[ti * 16] = bfr(acc[ti][r]);
    }
  }
}

// ---------------- head: 256-thread blocks (4 waves share one LDS fill) ----------------
__global__ __launch_bounds__(256) void head_kernel(const float* __restrict__ y,
                                                   const float* __restrict__ h2,
                                                   const float* __restrict__ Wc,
                                                   const float* __restrict__ bc,
                                                   const float* __restrict__ Wf,
                                                   float* __restrict__ out, int n) {
  __shared__ float sW[169 * CCLS];
  const int t = threadIdx.x;
  for (int i = t; i < 400; i += 256) ((float4*)sW)[i] = ((const float4*)Wc)[i];
  for (int i = t; i < 1280; i += 256)
    ((float4*)(sW + CCLS * CCLS))[i] = ((const float4*)(Wf + HDIM * CCLS))[i];
  if (t < 10) ((float4*)(sW + 168 * CCLS))[t] = ((const float4*)bc)[t];
  __syncthreads();

  const int node = blockIdx.x * 256 + t;
  const int nc = node < n ? node : n - 1;
  const float* zy = y + (size_t)nc * CCLS;
  const float* zh = h2 + (size_t)nc * HDIM;

  float acc[40];
#pragma unroll
  for (int cq = 0; cq < 10; ++cq) {
    float4 b4 = *(const float4*)&sW[168 * CCLS + cq * 4];
    acc[cq * 4 + 0] = b4.x; acc[cq * 4 + 1] = b4.y;
    acc[cq * 4 + 2] = b4.z; acc[cq * 4 + 3] = b4.w;
  }

#pragma unroll 2
  for (int kc = 0; kc < 10; ++kc) {      // y part: K = 40
    float4 zv = *(const float4*)(zy + kc * 4);
    float zj[4] = {zv.x, zv.y, zv.z, zv.w};
#pragma unroll
    for (int j = 0; j < 4; ++j) {
      const float* wr = sW + (kc * 4 + j) * CCLS;
#pragma unroll
      for (int cq = 0; cq < 10; ++cq) {
        float4 w4 = *(const float4*)(wr + cq * 4);
        acc[cq * 4 + 0] = fmaf(zj[j], w4.x, acc[cq * 4 + 0]);
        acc[cq * 4 + 1] = fmaf(zj[j], w4.y, acc[cq * 4 + 1]);
        acc[cq * 4 + 2] = fmaf(zj[j], w4.z, acc[cq * 4 + 2]);
        acc[cq * 4 + 3] = fmaf(zj[j], w4.w, acc[cq * 4 + 3]);
      }
    }
  }
#pragma unroll 2
  for (int kc = 0; kc < 32; ++kc) {      // h2 part: K = 128
    float4 zv = *(const float4*)(zh + kc * 4);
    float zj[4] = {zv.x, zv.y, zv.z, zv.w};
#pragma unroll
    for (int j = 0; j < 4; ++j) {
      const float* wr = sW + (40 + kc * 4 + j) * CCLS;
#pragma unroll
      for (int cq = 0; cq < 10; ++cq) {
        float4 w4 = *(const float4*)(wr + cq * 4);
        acc[cq * 4 + 0] = fmaf(zj[j], w4.x, acc[cq * 4 + 0]);
        acc[cq * 4 + 1] = fmaf(zj[j], w4.y, acc[cq * 4 + 1]);
        acc[cq * 4 + 2] = fmaf(zj[j], w4.z, acc[cq * 4 + 2]);
        acc[cq * 4 + 3] = fmaf(zj[j], w4.w, acc[cq * 4 + 3]);
      }
    }
  }

  // in-register softmax over 40 logits
  float m = acc[0];
#pragma unroll
  for (int c = 1; c < 40; ++c) m = fmaxf(m, acc[c]);
  float sum = 0.f;
#pragma unroll
  for (int c = 0; c < 40; ++c) { acc[c] = __expf(acc[c] - m); sum += acc[c]; }
  float inv = 1.0f / sum;
  if (node < n) {
    float* op = out + (size_t)node * CCLS;
#pragma unroll
    for (int cq = 0; cq < 10; ++cq) {
      float4 o = make_float4(acc[cq * 4 + 0] * inv, acc[cq * 4 + 1] * inv,
                             acc[cq * 4 + 2] * inv, acc[cq * 4 + 3] * inv);
      *(float4*)(op + cq * 4) = o;
    }
  }
}

extern "C" void kernel_launch(void* const* d_in, const int* in_sizes, int n_in,
                              void* d_out, int out_size, void* d_ws, size_t ws_size,
                              hipStream_t stream) {
  (void)n_in; (void)out_size; (void)ws_size;
  const float* features = (const float*)d_in[0];
  const int*   src      = (const int*)d_in[1];
  const int*   dst      = (const int*)d_in[2];
  const float* ew       = (const float*)d_in[3];
  const float* y        = (const float*)d_in[4];
  const float* W1       = (const float*)d_in[5];
  const float* b1       = (const float*)d_in[6];
  const float* W2       = (const float*)d_in[7];
  const float* b2       = (const float*)d_in[8];
  const float* We       = (const float*)d_in[9];
  const float* be       = (const float*)d_in[10];
  const float* Wf       = (const float*)d_in[11];
  const float* bf       = (const float*)d_in[12];
  float* out = (float*)d_out;

  const int n = in_sizes[0] / F_IN;   // 50000
  const int e = in_sizes[1];          // 1600000
  const int nb = (n + 63) >> 6;       // 782 buckets

  char* w = (char*)d_ws;
  auto take = [&](size_t bytes) {
    char* p = w;
    w += (bytes + 255) & ~(size_t)255;
    return p;
  };
  int*   gz       = (int*)take((size_t)2 * nb * 4);  // gcount | gcursor (one memset)
  int*   gcount   = gz;
  int*   gcursor  = gz + nb;
  int*   row_off  = (int*)take((size_t)(n + 1) * 4);
  uint2* ews      = (uint2*)take((size_t)e * 8);
  unsigned* ews2  = (unsigned*)take((size_t)(e + 16) * 4);
  unsigned short* bufH1  = (unsigned short*)take((size_t)n * HDIM * 2);
  unsigned short* bufH2  = (unsigned short*)take((size_t)n * HDIM * 2);
  float* bufS     = (float*)take((size_t)n * HDIM * 4);
  unsigned short* W1T = (unsigned short*)take((size_t)HDIM * F_IN * 2);
  unsigned short* W2T = (unsigned short*)take((size_t)HDIM * HDIM * 2);
  float* Wc       = (float*)take(CCLS * CCLS * 4);
  float* bc       = (float*)take(CCLS * 4);

  const int hb  = (e + EPB_H - 1) / EPB_H;           // 98 hist blocks
  const int nsb = (e + EPB - 1) / EPB;               // 196 scatter blocks
  const int ngb = (n + 63) / 64;                     // 782 gemm1 blocks
  const int G1  = ngb > 400 ? 400 : ngb;             // gemm1 with scatter
  const int G2  = ngb - G1;                          // gemm1 with sort

  hipMemsetAsync(gz, 0, (size_t)2 * nb * 4, stream);
  prep_kernel<<<128 + hb, 256, 0, stream>>>(W1, W1T, dst, gcount, e, nb);
  scatter_gemm1<<<nsb + G1, 256, 0, stream>>>(src, dst, ew, gcount, gcursor, ews,
                                              features, W1T, bufH1, e, nb, nsb, n);
  sort_misc<<<nb + G2 + 64 + 2, 256, 0, stream>>>(ews, gcount, ews2, row_off,
                                                  features, W1T, bufH1,
                                                  W2, W2T, We, be, Wf, bf, Wc, bc,
                                                  n, nb, G1, G2, n);

  spmm_bf16<1><<<(n + 3) / 4, 256, 0, stream>>>(bufH1, ews2, row_off, b1, bufH2, n, 1);
  gemm_mfma<HDIM><<<(n + 63) / 64, 256, 0, stream>>>(bufH2, W2T, bufH1, n);
  spmm_bf16<0><<<(n + 3) / 4, 256, 0, stream>>>(bufH1, ews2, row_off, b2, bufS, n, 0);
  head_kernel<<<(n + 255) / 256, 256, 0, stream>>>(y, bufS, Wc, bc, Wf, out, n);
}

// Round 8
// 343.882 us; speedup vs baseline: 1.2369x; 1.0682x over previous
//
#include <hip/hip_runtime.h>
#include <hip/hip_bf16.h>
#include <hip/hip_fp16.h>
#include <cstdint>
#include <cstddef>
#include <cmath>

#define F_IN 256
#define HDIM 128
#define CCLS 40
#define NBMAX 1024   // max buckets (n<=65536); n=50000 -> 782
#define EPB 4096     // edges per scatter block
#define CAP 4096     // slots per bucket (mean load 2048 -> 2x headroom)

typedef short bf16x8 __attribute__((ext_vector_type(8)));
typedef float f32x4 __attribute__((ext_vector_type(4)));

__device__ inline unsigned pkbf(float a, float b) {
  __hip_bfloat162 h = __float22bfloat162_rn(make_float2(a, b));
  unsigned u;
  __builtin_memcpy(&u, &h, 4);
  return u;
}
__device__ inline unsigned short bfr(float f) {
  __hip_bfloat16 h = __float2bfloat16(f);
  unsigned short u;
  __builtin_memcpy(&u, &h, 2);
  return u;
}
__device__ inline float f16tof(unsigned short hb) {
  __half hv;
  __builtin_memcpy(&hv, &hb, 2);
  return __half2float(hv);
}
__device__ inline unsigned short ftof16(float f) {
  __half hv = __float2half(f);
  unsigned short u;
  __builtin_memcpy(&u, &hv, 2);
  return u;
}

// ---- gemm1 fused body: normalize 16 rows/wave into LDS, MFMA C[64][128] ----
__device__ inline void gemm1_body(char* smem, int bm0, const float* __restrict__ X,
                                  const unsigned short* __restrict__ WT,
                                  unsigned short* __restrict__ C, int M, int t) {
  unsigned short (*As)[264] = (unsigned short(*)[264])smem;
  const int w8 = t >> 6, l = t & 63;

  for (int rr = 0; rr < 16; ++rr) {
    int row = w8 * 16 + rr;
    int grow = bm0 + row;
    const float* p = X + (size_t)(grow < M ? grow : (M - 1)) * F_IN + l * 4;
    float4 v = *(const float4*)p;
    float s = v.x * v.x + v.y * v.y + v.z * v.z + v.w * v.w;
#pragma unroll
    for (int off = 32; off; off >>= 1) s += __shfl_xor(s, off, 64);
    float inv = 1.0f / fmaxf(sqrtf(s), 1e-12f);
    *(uint2*)&As[row][l * 4] =
        make_uint2(pkbf(v.x * inv, v.y * inv), pkbf(v.z * inv, v.w * inv));
  }

  const int ln = l & 15, quad = l >> 4;
  const int m0 = bm0 + w8 * 16;
  f32x4 acc[8];
#pragma unroll
  for (int i = 0; i < 8; ++i) acc[i] = (f32x4){0.f, 0.f, 0.f, 0.f};

#pragma unroll
  for (int k0 = 0; k0 < F_IN; k0 += 32) {
    bf16x8 af = *(const bf16x8*)&As[w8 * 16 + ln][k0 + quad * 8];
#pragma unroll
    for (int ti = 0; ti < 8; ++ti) {
      bf16x8 bfv = *(const bf16x8*)(WT + (size_t)(ti * 16 + ln) * F_IN + k0 + quad * 8);
      acc[ti] = __builtin_amdgcn_mfma_f32_16x16x32_bf16(af, bfv, acc[ti], 0, 0, 0);
    }
  }

#pragma unroll
  for (int r = 0; r < 4; ++r) {
    int grow = m0 + quad * 4 + r;
    if (grow < M) {
      unsigned short* cp = C + (size_t)grow * HDIM + ln;
#pragma unroll
      for (int ti = 0; ti < 8; ++ti) cp[ti * 16] = bfr(acc[ti][r]);
    }
  }
}

// ---- prep: W1T transpose (128 blocks) | zero bucket cursors (1 block) ----
__global__ __launch_bounds__(256) void prep_kernel(const float* __restrict__ W1,
                                                   unsigned short* __restrict__ W1T,
                                                   int* __restrict__ gcursor, int nb) {
  const int b = blockIdx.x;
  const int t = threadIdx.x;
  if (b < 128) {
    int idx = b * 256 + t;
    int nr = idx >> 8, k = idx & 255;
    W1T[idx] = bfr(W1[k * 128 + nr]);
  } else {
    for (int i = t; i < nb; i += 256) gcursor[i] = 0;
  }
}

// ---- dispatch 2: slotted scatter (nsb) | gemm1 (ngb) | W2T (64) | Wc fold (2) ----
// Scatter: bucket b owns ews slots [b*CAP, ...). Per-edge rank = return value of
// the LDS hist atomicAdd (no second atomic pass, no scan). sort depends only on
// scatter blocks; gemm1/W2T/Wc fully independent.
__global__ __launch_bounds__(256) void scatter_gemm1(const int* __restrict__ src,
                                                     const int* __restrict__ dst,
                                                     const float* __restrict__ w,
                                                     int* __restrict__ gcursor,
                                                     uint2* __restrict__ ews,
                                                     const float* __restrict__ X,
                                                     const unsigned short* __restrict__ W1T,
                                                     unsigned short* __restrict__ C,
                                                     const float* __restrict__ W2,
                                                     unsigned short* __restrict__ W2T,
                                                     const float* __restrict__ We,
                                                     const float* __restrict__ be,
                                                     const float* __restrict__ Wf,
                                                     const float* __restrict__ bf,
                                                     float* __restrict__ Wc,
                                                     float* __restrict__ bc,
                                                     int e, int nb, int nsb, int ngb,
                                                     int M) {
  __shared__ char smem[64 * 264 * 2];   // gemm1 A-tile; scatter uses first 8KB
  const int t = threadIdx.x;
  const int b = blockIdx.x;
  if (b < nsb) {
    // ================= slotted multisplit scatter =================
    int* hist = (int*)smem;        // [NBMAX]
    int* sb   = hist + NBMAX;      // [NBMAX]
    for (int i = t; i < nb; i += 256) hist[i] = 0;
    __syncthreads();
    const int b4 = b * (EPB / 4);
    int4 dv[4];
    int rk[16];
#pragma unroll
    for (int k = 0; k < 4; ++k) {
      int gi = b4 + k * 256 + t;
      int e0 = gi * 4;
      int4 d = make_int4(-1, -1, -1, -1);
      if (e0 + 3 < e) d = ((const int4*)dst)[gi];
      else if (e0 < e) {
        d.x = dst[e0];
        if (e0 + 1 < e) d.y = dst[e0 + 1];
        if (e0 + 2 < e) d.z = dst[e0 + 2];
      }
      dv[k] = d;
      rk[k * 4 + 0] = (d.x >= 0) ? atomicAdd(&hist[d.x >> 6], 1) : 0;
      rk[k * 4 + 1] = (d.y >= 0) ? atomicAdd(&hist[d.y >> 6], 1) : 0;
      rk[k * 4 + 2] = (d.z >= 0) ? atomicAdd(&hist[d.z >> 6], 1) : 0;
      rk[k * 4 + 3] = (d.w >= 0) ? atomicAdd(&hist[d.w >> 6], 1) : 0;
    }
    __syncthreads();
    for (int i = t; i < nb; i += 256) {
      int c = hist[i];
      sb[i] = i * CAP + (c ? atomicAdd(&gcursor[i], c) : 0);
    }
    __syncthreads();
#pragma unroll
    for (int k = 0; k < 4; ++k) {
      int gi = b4 + k * 256 + t;
      int e0 = gi * 4;
      if (e0 >= e) continue;
      int4 s4 = make_int4(0, 0, 0, 0);
      float4 w4 = make_float4(0.f, 0.f, 0.f, 0.f);
      if (e0 + 3 < e) { s4 = ((const int4*)src)[gi]; w4 = ((const float4*)w)[gi]; }
      else {
        s4.x = src[e0]; w4.x = w[e0];
        if (e0 + 1 < e) { s4.y = src[e0 + 1]; w4.y = w[e0 + 1]; }
        if (e0 + 2 < e) { s4.z = src[e0 + 2]; w4.z = w[e0 + 2]; }
      }
      int4 d = dv[k];
      if (d.x >= 0) ews[sb[d.x >> 6] + rk[k * 4 + 0]] =
          make_uint2(((unsigned)(d.x & 63) << 26) | (unsigned)s4.x, __float_as_uint(w4.x));
      if (d.y >= 0) ews[sb[d.y >> 6] + rk[k * 4 + 1]] =
          make_uint2(((unsigned)(d.y & 63) << 26) | (unsigned)s4.y, __float_as_uint(w4.y));
      if (d.z >= 0) ews[sb[d.z >> 6] + rk[k * 4 + 2]] =
          make_uint2(((unsigned)(d.z & 63) << 26) | (unsigned)s4.z, __float_as_uint(w4.z));
      if (d.w >= 0) ews[sb[d.w >> 6] + rk[k * 4 + 3]] =
          make_uint2(((unsigned)(d.w & 63) << 26) | (unsigned)s4.w, __float_as_uint(w4.w));
    }
  } else if (b < nsb + ngb) {
    gemm1_body(smem, (b - nsb) * 64, X, W1T, C, M, t);
  } else if (b < nsb + ngb + 64) {
    int idx = (b - nsb - ngb) * 256 + t;   // W2T transpose (128x128)
    int nr = idx >> 7, k = idx & 127;
    W2T[idx] = bfr(W2[k * 128 + nr]);
  } else {
    int part = b - (nsb + ngb + 64);       // Wc = We @ Wf_top fold + bc
    int lo = part * 800, hi = lo + 800;
    for (int i = lo + t; i < hi; i += 256) {
      int c = i / CCLS, j = i % CCLS;
      float s = 0.f;
      for (int f = 0; f < HDIM; ++f) s += We[c * HDIM + f] * Wf[f * CCLS + j];
      Wc[i] = s;
    }
    if (part == 0 && t < CCLS) {
      float s = bf[t];
      for (int f = 0; f < HDIM; ++f) s += be[f] * Wf[f * CCLS + t];
      bc[t] = s;
    }
  }
}

// ---- bucket_sort: slotted segment, per-wave counters, wave-parallel scan, small LDS ----
__global__ __launch_bounds__(256) void bucket_sort(const uint2* __restrict__ ews,
                                                   const int* __restrict__ gcursor,
                                                   unsigned* __restrict__ ews2,
                                                   int* __restrict__ row_off,
                                                   int* __restrict__ row_end,
                                                   int n, int nb) {
  __shared__ int cnt[256];   // [4 waves][64]
  __shared__ int cur[64];
  const int t = threadIdx.x;
  const int b = blockIdx.x;
  cnt[t] = 0;
  __syncthreads();
  const int base = b * CAP;
  const int c = gcursor[b];
  const int wv = t >> 6;
  for (int i = t; i < c; i += 256)
    atomicAdd(&cnt[wv * 64 + ((unsigned)ews[base + i].x >> 26)], 1);
  __syncthreads();
  if (t < 64) {
    int tot = cnt[t] + cnt[64 + t] + cnt[128 + t] + cnt[192 + t];
    int x = tot;
#pragma unroll
    for (int off = 1; off < 64; off <<= 1) {
      int y = __shfl_up(x, off, 64);
      if (t >= off) x += y;
    }
    int excl = x - tot;
    cur[t] = excl;
    int node = b * 64 + t;
    if (node < n) { row_off[node] = base + excl; row_end[node] = base + excl + tot; }
  }
  __syncthreads();
  for (int i = t; i < c; i += 256) {
    uint2 p = ews[base + i];
    int d = (unsigned)p.x >> 26;
    int pos = base + atomicAdd(&cur[d], 1);
    ews2[pos] = (p.x & 0xFFFFu) | ((unsigned)ftof16(__uint_as_float(p.y)) << 16);
  }
}

// decode + gather + fma for a pair of packed edge records (half selects)
#define SPMM_PAIR(ua, ub)                                                      \
  {                                                                            \
    unsigned u = half ? (ub) : (ua);                                           \
    float wt = f16tof((unsigned short)(u >> 16));                              \
    const uint2 xv = *(const uint2*)(xin + (size_t)(u & 0xFFFFu) * HDIM + fo); \
    acc.x = fmaf(wt, __uint_as_float(xv.x << 16), acc.x);                      \
    acc.y = fmaf(wt, __uint_as_float(xv.x & 0xFFFF0000u), acc.y);              \
    acc.z = fmaf(wt, __uint_as_float(xv.y << 16), acc.z);                      \
    acc.w = fmaf(wt, __uint_as_float(xv.y & 0xFFFF0000u), acc.w);              \
  }

// ---------------- SPMM v2 (proven): full-width, wave/node, 16-edge unroll ----------------
template <int OUT_BF16>
__global__ __launch_bounds__(256) void spmm_bf16(const unsigned short* __restrict__ xin,
                                                 const unsigned* __restrict__ ews,
                                                 const int* __restrict__ row_off,
                                                 const int* __restrict__ row_end,
                                                 const float* __restrict__ bias,
                                                 void* __restrict__ outp, int n,
                                                 int do_relu) {
  const int t = threadIdx.x;
  const int l = t & 63;
  const int node = blockIdx.x * 4 + (t >> 6);
  if (node >= n) return;
  const int ue0 = __builtin_amdgcn_readfirstlane(row_off[node]);
  const int ue1 = __builtin_amdgcn_readfirstlane(row_end[node]);
  const int cnt = ue1 - ue0;
  const unsigned* ep = ews + ue0;              // wave-uniform -> scalar loads
  const int fo = (l & 31) * 4;
  const int half = l >> 5;
  float4 acc = make_float4(0.f, 0.f, 0.f, 0.f);

  int k = 0;
  for (; k + 16 <= cnt; k += 16) {             // 8 independent gathers in flight
    unsigned a0 = ep[k + 0], a1 = ep[k + 1], a2 = ep[k + 2], a3 = ep[k + 3];
    unsigned a4 = ep[k + 4], a5 = ep[k + 5], a6 = ep[k + 6], a7 = ep[k + 7];
    unsigned a8 = ep[k + 8], a9 = ep[k + 9], a10 = ep[k + 10], a11 = ep[k + 11];
    unsigned a12 = ep[k + 12], a13 = ep[k + 13], a14 = ep[k + 14], a15 = ep[k + 15];
    SPMM_PAIR(a0, a1);
    SPMM_PAIR(a2, a3);
    SPMM_PAIR(a4, a5);
    SPMM_PAIR(a6, a7);
    SPMM_PAIR(a8, a9);
    SPMM_PAIR(a10, a11);
    SPMM_PAIR(a12, a13);
    SPMM_PAIR(a14, a15);
  }
  for (; k + 8 <= cnt; k += 8) {
    unsigned a0 = ep[k + 0], a1 = ep[k + 1], a2 = ep[k + 2], a3 = ep[k + 3];
    unsigned a4 = ep[k + 4], a5 = ep[k + 5], a6 = ep[k + 6], a7 = ep[k + 7];
    SPMM_PAIR(a0, a1);
    SPMM_PAIR(a2, a3);
    SPMM_PAIR(a4, a5);
    SPMM_PAIR(a6, a7);
  }
  for (; k < cnt; k += 2) {
    unsigned a0 = ep[k];
    unsigned a1 = (k + 1 < cnt) ? ep[k + 1] : 0u;  // w=+0, src=0 -> safe
    SPMM_PAIR(a0, a1);
  }

  acc.x += __shfl_xor(acc.x, 32, 64);
  acc.y += __shfl_xor(acc.y, 32, 64);
  acc.z += __shfl_xor(acc.z, 32, 64);
  acc.w += __shfl_xor(acc.w, 32, 64);
  if (l < 32) {
    float4 bv = *(const float4*)(bias + fo);
    float4 r = make_float4(acc.x + bv.x, acc.y + bv.y, acc.z + bv.z, acc.w + bv.w);
    if (do_relu) {
      r.x = fmaxf(r.x, 0.f); r.y = fmaxf(r.y, 0.f);
      r.z = fmaxf(r.z, 0.f); r.w = fmaxf(r.w, 0.f);
    }
    if (OUT_BF16) {
      uint2 o = make_uint2(pkbf(r.x, r.y), pkbf(r.z, r.w));
      *(uint2*)((unsigned short*)outp + (size_t)node * HDIM + fo) = o;
    } else {
      *(float4*)((float*)outp + (size_t)node * HDIM + fo) = r;
    }
  }
}

// ---------------- MFMA GEMM: C[M][128] = A[M][K](bf16) @ WT[128][K](bf16) ----------------
template <int K>
__global__ __launch_bounds__(256) void gemm_mfma(const unsigned short* __restrict__ A,
                                                 const unsigned short* __restrict__ WT,
                                                 unsigned short* __restrict__ C, int M) {
  const int t = threadIdx.x;
  const int w = t >> 6, l = t & 63;
  const int ln = l & 15, quad = l >> 4;
  const int m0 = blockIdx.x * 64 + w * 16;
  const int arow = m0 + ln;
  const unsigned short* aptr = A + (size_t)(arow < M ? arow : (M - 1)) * K + quad * 8;

  f32x4 acc[8];
#pragma unroll
  for (int i = 0; i < 8; ++i) acc[i] = (f32x4){0.f, 0.f, 0.f, 0.f};

#pragma unroll
  for (int k0 = 0; k0 < K; k0 += 32) {
    bf16x8 af = *(const bf16x8*)(aptr + k0);
#pragma unroll
    for (int ti = 0; ti < 8; ++ti) {
      bf16x8 bfv = *(const bf16x8*)(WT + (size_t)(ti * 16 + ln) * K + k0 + quad * 8);
      acc[ti] = __builtin_amdgcn_mfma_f32_16x16x32_bf16(af, bfv, acc[ti], 0, 0, 0);
    }
  }

#pragma unroll
  for (int r = 0; r < 4; ++r) {
    int grow = m0 + quad * 4 + r;
    if (grow < M) {
      unsigned short* cp = C + (size_t)grow * HDIM + ln;
#pragma unroll
      for (int ti = 0; ti < 8; ++ti) cp[ti * 16] = bfr(acc[ti][r]);
    }
  }
}

// ---------------- head: 256-thread blocks (4 waves share one LDS fill) ----------------
__global__ __launch_bounds__(256) void head_kernel(const float* __restrict__ y,
                                                   const float* __restrict__ h2,
                                                   const float* __restrict__ Wc,
                                                   const float* __restrict__ bc,
                                                   const float* __restrict__ Wf,
                                                   float* __restrict__ out, int n) {
  __shared__ float sW[169 * CCLS];
  const int t = threadIdx.x;
  for (int i = t; i < 400; i += 256) ((float4*)sW)[i] = ((const float4*)Wc)[i];
  for (int i = t; i < 1280; i += 256)
    ((float4*)(sW + CCLS * CCLS))[i] = ((const float4*)(Wf + HDIM * CCLS))[i];
  if (t < 10) ((float4*)(sW + 168 * CCLS))[t] = ((const float4*)bc)[t];
  __syncthreads();

  const int node = blockIdx.x * 256 + t;
  const int nc = node < n ? node : n - 1;
  const float* zy = y + (size_t)nc * CCLS;
  const float* zh = h2 + (size_t)nc * HDIM;

  float acc[40];
#pragma unroll
  for (int cq = 0; cq < 10; ++cq) {
    float4 b4 = *(const float4*)&sW[168 * CCLS + cq * 4];
    acc[cq * 4 + 0] = b4.x; acc[cq * 4 + 1] = b4.y;
    acc[cq * 4 + 2] = b4.z; acc[cq * 4 + 3] = b4.w;
  }

#pragma unroll 2
  for (int kc = 0; kc < 10; ++kc) {      // y part: K = 40
    float4 zv = *(const float4*)(zy + kc * 4);
    float zj[4] = {zv.x, zv.y, zv.z, zv.w};
#pragma unroll
    for (int j = 0; j < 4; ++j) {
      const float* wr = sW + (kc * 4 + j) * CCLS;
#pragma unroll
      for (int cq = 0; cq < 10; ++cq) {
        float4 w4 = *(const float4*)(wr + cq * 4);
        acc[cq * 4 + 0] = fmaf(zj[j], w4.x, acc[cq * 4 + 0]);
        acc[cq * 4 + 1] = fmaf(zj[j], w4.y, acc[cq * 4 + 1]);
        acc[cq * 4 + 2] = fmaf(zj[j], w4.z, acc[cq * 4 + 2]);
        acc[cq * 4 + 3] = fmaf(zj[j], w4.w, acc[cq * 4 + 3]);
      }
    }
  }
#pragma unroll 2
  for (int kc = 0; kc < 32; ++kc) {      // h2 part: K = 128
    float4 zv = *(const float4*)(zh + kc * 4);
    float zj[4] = {zv.x, zv.y, zv.z, zv.w};
#pragma unroll
    for (int j = 0; j < 4; ++j) {
      const float* wr = sW + (40 + kc * 4 + j) * CCLS;
#pragma unroll
      for (int cq = 0; cq < 10; ++cq) {
        float4 w4 = *(const float4*)(wr + cq * 4);
        acc[cq * 4 + 0] = fmaf(zj[j], w4.x, acc[cq * 4 + 0]);
        acc[cq * 4 + 1] = fmaf(zj[j], w4.y, acc[cq * 4 + 1]);
        acc[cq * 4 + 2] = fmaf(zj[j], w4.z, acc[cq * 4 + 2]);
        acc[cq * 4 + 3] = fmaf(zj[j], w4.w, acc[cq * 4 + 3]);
      }
    }
  }

  // in-register softmax over 40 logits
  float m = acc[0];
#pragma unroll
  for (int c = 1; c < 40; ++c) m = fmaxf(m, acc[c]);
  float sum = 0.f;
#pragma unroll
  for (int c = 0; c < 40; ++c) { acc[c] = __expf(acc[c] - m); sum += acc[c]; }
  float inv = 1.0f / sum;
  if (node < n) {
    float* op = out + (size_t)node * CCLS;
#pragma unroll
    for (int cq = 0; cq < 10; ++cq) {
      float4 o = make_float4(acc[cq * 4 + 0] * inv, acc[cq * 4 + 1] * inv,
                             acc[cq * 4 + 2] * inv, acc[cq * 4 + 3] * inv);
      *(float4*)(op + cq * 4) = o;
    }
  }
}

extern "C" void kernel_launch(void* const* d_in, const int* in_sizes, int n_in,
                              void* d_out, int out_size, void* d_ws, size_t ws_size,
                              hipStream_t stream) {
  (void)n_in; (void)out_size; (void)ws_size;
  const float* features = (const float*)d_in[0];
  const int*   src      = (const int*)d_in[1];
  const int*   dst      = (const int*)d_in[2];
  const float* ew       = (const float*)d_in[3];
  const float* y        = (const float*)d_in[4];
  const float* W1       = (const float*)d_in[5];
  const float* b1       = (const float*)d_in[6];
  const float* W2       = (const float*)d_in[7];
  const float* b2       = (const float*)d_in[8];
  const float* We       = (const float*)d_in[9];
  const float* be       = (const float*)d_in[10];
  const float* Wf       = (const float*)d_in[11];
  const float* bf       = (const float*)d_in[12];
  float* out = (float*)d_out;

  const int n = in_sizes[0] / F_IN;   // 50000
  const int e = in_sizes[1];          // 1600000
  const int nb = (n + 63) >> 6;       // 782 buckets

  char* w = (char*)d_ws;
  auto take = [&](size_t bytes) {
    char* p = w;
    w += (bytes + 255) & ~(size_t)255;
    return p;
  };
  int*   gcursor  = (int*)take((size_t)nb * 4);
  int*   row_off  = (int*)take((size_t)n * 4);
  int*   row_end  = (int*)take((size_t)n * 4);
  uint2* ews      = (uint2*)take((size_t)nb * CAP * 8);
  unsigned* ews2  = (unsigned*)take((size_t)nb * CAP * 4);
  unsigned short* bufH1  = (unsigned short*)take((size_t)n * HDIM * 2);
  unsigned short* bufH2  = (unsigned short*)take((size_t)n * HDIM * 2);
  float* bufS     = (float*)take((size_t)n * HDIM * 4);
  unsigned short* W1T = (unsigned short*)take((size_t)HDIM * F_IN * 2);
  unsigned short* W2T = (unsigned short*)take((size_t)HDIM * HDIM * 2);
  float* Wc       = (float*)take(CCLS * CCLS * 4);
  float* bc       = (float*)take(CCLS * 4);

  const int nsb = (e + EPB - 1) / EPB;               // 391 scatter blocks
  const int ngb = (n + 63) / 64;                     // 782 gemm1 blocks

  prep_kernel<<<129, 256, 0, stream>>>(W1, W1T, gcursor, nb);
  scatter_gemm1<<<nsb + ngb + 64 + 2, 256, 0, stream>>>(
      src, dst, ew, gcursor, ews, features, W1T, bufH1,
      W2, W2T, We, be, Wf, bf, Wc, bc, e, nb, nsb, ngb, n);
  bucket_sort<<<nb, 256, 0, stream>>>(ews, gcursor, ews2, row_off, row_end, n, nb);

  spmm_bf16<1><<<(n + 3) / 4, 256, 0, stream>>>(bufH1, ews2, row_off, row_end, b1,
                                                bufH2, n, 1);
  gemm_mfma<HDIM><<<(n + 63) / 64, 256, 0, stream>>>(bufH2, W2T, bufH1, n);
  spmm_bf16<0><<<(n + 3) / 4, 256, 0, stream>>>(bufH1, ews2, row_off, row_end, b2,
                                                bufS, n, 0);
  head_kernel<<<(n + 255) / 256, 256, 0, stream>>>(y, bufS, Wc, bc, Wf, out, n);
}

// Round 9
// 325.321 us; speedup vs baseline: 1.3075x; 1.0571x over previous
//
#include <hip/hip_runtime.h>
#include <hip/hip_bf16.h>
#include <hip/hip_fp16.h>
#include <cstdint>
#include <cstddef>
#include <cmath>

#define F_IN 256
#define HDIM 128
#define CCLS 40
#define NBMAX 1024   // max buckets (n<=65536); n=50000 -> 782
#define EPB 8192     // edges per scatter block
#define CAP 4096     // slots per bucket (mean load 2048 -> 2x headroom)

typedef short bf16x8 __attribute__((ext_vector_type(8)));
typedef float f32x4 __attribute__((ext_vector_type(4)));

__device__ inline unsigned pkbf(float a, float b) {
  __hip_bfloat162 h = __float22bfloat162_rn(make_float2(a, b));
  unsigned u;
  __builtin_memcpy(&u, &h, 4);
  return u;
}
__device__ inline unsigned short bfr(float f) {
  __hip_bfloat16 h = __float2bfloat16(f);
  unsigned short u;
  __builtin_memcpy(&u, &h, 2);
  return u;
}
__device__ inline float f16tof(unsigned short hb) {
  __half hv;
  __builtin_memcpy(&hv, &hb, 2);
  return __half2float(hv);
}
__device__ inline unsigned short ftof16(float f) {
  __half hv = __float2half(f);
  unsigned short u;
  __builtin_memcpy(&u, &hv, 2);
  return u;
}

// ---- prep: W1T transpose (128 blocks) | zero bucket cursors (1 block) ----
__global__ __launch_bounds__(256) void prep_kernel(const float* __restrict__ W1,
                                                   unsigned short* __restrict__ W1T,
                                                   int* __restrict__ gcursor, int nb) {
  const int b = blockIdx.x;
  const int t = threadIdx.x;
  if (b < 128) {
    int idx = b * 256 + t;
    int nr = idx >> 8, k = idx & 255;
    W1T[idx] = bfr(W1[k * 128 + nr]);
  } else {
    for (int i = t; i < nb; i += 256) gcursor[i] = 0;
  }
}

// ---- dispatch 2: slotted scatter (nsb) | gemm1 16-row tiles (ngb) | W2T | Wc fold ----
// gemm1 tile shrunk to 16 rows -> LDS 8.4KB so the merged kernel runs ~5 blocks/CU
// (round-8's 33.8KB tile capped everything at 4 blocks/CU, 30% occupancy).
__global__ __launch_bounds__(256) void scatter_gemm1(const int* __restrict__ src,
                                                     const int* __restrict__ dst,
                                                     const float* __restrict__ w,
                                                     int* __restrict__ gcursor,
                                                     uint2* __restrict__ ews,
                                                     const float* __restrict__ X,
                                                     const unsigned short* __restrict__ W1T,
                                                     unsigned short* __restrict__ C,
                                                     const float* __restrict__ W2,
                                                     unsigned short* __restrict__ W2T,
                                                     const float* __restrict__ We,
                                                     const float* __restrict__ be,
                                                     const float* __restrict__ Wf,
                                                     const float* __restrict__ bf,
                                                     float* __restrict__ Wc,
                                                     float* __restrict__ bc,
                                                     int e, int nb, int nsb, int ngb,
                                                     int M) {
  __shared__ char smem[16 * 264 * 2];   // union: gemm1 A-tile (8448B) | scatter hist+sb (8KB)
  const int t = threadIdx.x;
  const int b = blockIdx.x;
  if (b < nsb) {
    // ================= slotted multisplit scatter (rank = hist atomic return) =========
    int* hist = (int*)smem;        // [NBMAX]
    int* sb   = hist + NBMAX;      // [NBMAX]
    for (int i = t; i < nb; i += 256) hist[i] = 0;
    __syncthreads();
    const int b4 = b * (EPB / 4);
    int4 dv[8];
    int rk[32];
#pragma unroll
    for (int k = 0; k < 8; ++k) {
      int gi = b4 + k * 256 + t;
      int e0 = gi * 4;
      int4 d = make_int4(-1, -1, -1, -1);
      if (e0 + 3 < e) d = ((const int4*)dst)[gi];
      else if (e0 < e) {
        d.x = dst[e0];
        if (e0 + 1 < e) d.y = dst[e0 + 1];
        if (e0 + 2 < e) d.z = dst[e0 + 2];
      }
      dv[k] = d;
      rk[k * 4 + 0] = (d.x >= 0) ? atomicAdd(&hist[d.x >> 6], 1) : 0;
      rk[k * 4 + 1] = (d.y >= 0) ? atomicAdd(&hist[d.y >> 6], 1) : 0;
      rk[k * 4 + 2] = (d.z >= 0) ? atomicAdd(&hist[d.z >> 6], 1) : 0;
      rk[k * 4 + 3] = (d.w >= 0) ? atomicAdd(&hist[d.w >> 6], 1) : 0;
    }
    __syncthreads();
    for (int i = t; i < nb; i += 256) {
      int c = hist[i];
      sb[i] = i * CAP + (c ? atomicAdd(&gcursor[i], c) : 0);
    }
    __syncthreads();
#pragma unroll
    for (int k = 0; k < 8; ++k) {
      int gi = b4 + k * 256 + t;
      int e0 = gi * 4;
      if (e0 >= e) continue;
      int4 s4 = make_int4(0, 0, 0, 0);
      float4 w4 = make_float4(0.f, 0.f, 0.f, 0.f);
      if (e0 + 3 < e) { s4 = ((const int4*)src)[gi]; w4 = ((const float4*)w)[gi]; }
      else {
        s4.x = src[e0]; w4.x = w[e0];
        if (e0 + 1 < e) { s4.y = src[e0 + 1]; w4.y = w[e0 + 1]; }
        if (e0 + 2 < e) { s4.z = src[e0 + 2]; w4.z = w[e0 + 2]; }
      }
      int4 d = dv[k];
      if (d.x >= 0) ews[sb[d.x >> 6] + rk[k * 4 + 0]] =
          make_uint2(((unsigned)(d.x & 63) << 26) | (unsigned)s4.x, __float_as_uint(w4.x));
      if (d.y >= 0) ews[sb[d.y >> 6] + rk[k * 4 + 1]] =
          make_uint2(((unsigned)(d.y & 63) << 26) | (unsigned)s4.y, __float_as_uint(w4.y));
      if (d.z >= 0) ews[sb[d.z >> 6] + rk[k * 4 + 2]] =
          make_uint2(((unsigned)(d.z & 63) << 26) | (unsigned)s4.z, __float_as_uint(w4.z));
      if (d.w >= 0) ews[sb[d.w >> 6] + rk[k * 4 + 3]] =
          make_uint2(((unsigned)(d.w & 63) << 26) | (unsigned)s4.w, __float_as_uint(w4.w));
    }
  } else if (b < nsb + ngb) {
    // ================= gemm1: fused norm + MFMA, 16-row tile =================
    unsigned short (*As)[264] = (unsigned short(*)[264])smem;
    const int w8 = t >> 6, l = t & 63;
    const int bm0 = (b - nsb) * 16;
    // norm phase: wave w handles rows w*4 .. w*4+3
    for (int rr = 0; rr < 4; ++rr) {
      int row = w8 * 4 + rr;
      int grow = bm0 + row;
      const float* p = X + (size_t)(grow < M ? grow : (M - 1)) * F_IN + l * 4;
      float4 v = *(const float4*)p;
      float s = v.x * v.x + v.y * v.y + v.z * v.z + v.w * v.w;
#pragma unroll
      for (int off = 32; off; off >>= 1) s += __shfl_xor(s, off, 64);
      float inv = 1.0f / fmaxf(sqrtf(s), 1e-12f);
      *(uint2*)&As[row][l * 4] =
          make_uint2(pkbf(v.x * inv, v.y * inv), pkbf(v.z * inv, v.w * inv));
    }
    __syncthreads();
    // MFMA phase: wave w computes cols [w*32, w*32+32), all 16 rows
    const int ln = l & 15, quad = l >> 4;
    f32x4 acc[2];
    acc[0] = (f32x4){0.f, 0.f, 0.f, 0.f};
    acc[1] = (f32x4){0.f, 0.f, 0.f, 0.f};
#pragma unroll
    for (int k0 = 0; k0 < F_IN; k0 += 32) {
      bf16x8 af = *(const bf16x8*)&As[ln][k0 + quad * 8];
#pragma unroll
      for (int ti = 0; ti < 2; ++ti) {
        bf16x8 bfv = *(const bf16x8*)(W1T + (size_t)(w8 * 32 + ti * 16 + ln) * F_IN +
                                      k0 + quad * 8);
        acc[ti] = __builtin_amdgcn_mfma_f32_16x16x32_bf16(af, bfv, acc[ti], 0, 0, 0);
      }
    }
#pragma unroll
    for (int r = 0; r < 4; ++r) {
      int grow = bm0 + quad * 4 + r;
      if (grow < M) {
#pragma unroll
        for (int ti = 0; ti < 2; ++ti)
          C[(size_t)grow * HDIM + w8 * 32 + ti * 16 + ln] = bfr(acc[ti][r]);
      }
    }
  } else if (b < nsb + ngb + 64) {
    int idx = (b - nsb - ngb) * 256 + t;   // W2T transpose (128x128)
    int nr = idx >> 7, k = idx & 127;
    W2T[idx] = bfr(W2[k * 128 + nr]);
  } else {
    int part = b - (nsb + ngb + 64);       // Wc = We @ Wf_top fold + bc
    int lo = part * 800, hi = lo + 800;
    for (int i = lo + t; i < hi; i += 256) {
      int c = i / CCLS, j = i % CCLS;
      float s = 0.f;
      for (int f = 0; f < HDIM; ++f) s += We[c * HDIM + f] * Wf[f * CCLS + j];
      Wc[i] = s;
    }
    if (part == 0 && t < CCLS) {
      float s = bf[t];
      for (int f = 0; f < HDIM; ++f) s += be[f] * Wf[f * CCLS + t];
      bc[t] = s;
    }
  }
}

// ---- bucket_sort: slotted segment, per-wave counters, wave-parallel scan ----
__global__ __launch_bounds__(256) void bucket_sort(const uint2* __restrict__ ews,
                                                   const int* __restrict__ gcursor,
                                                   unsigned* __restrict__ ews2,
                                                   int* __restrict__ row_off,
                                                   int* __restrict__ row_end,
                                                   int n, int nb) {
  __shared__ int cnt[256];   // [4 waves][64]
  __shared__ int cur[64];
  const int t = threadIdx.x;
  const int b = blockIdx.x;
  cnt[t] = 0;
  __syncthreads();
  const int base = b * CAP;
  const int c = gcursor[b];
  const int wv = t >> 6;
  for (int i = t; i < c; i += 256)
    atomicAdd(&cnt[wv * 64 + ((unsigned)ews[base + i].x >> 26)], 1);
  __syncthreads();
  if (t < 64) {
    int tot = cnt[t] + cnt[64 + t] + cnt[128 + t] + cnt[192 + t];
    int x = tot;
#pragma unroll
    for (int off = 1; off < 64; off <<= 1) {
      int y = __shfl_up(x, off, 64);
      if (t >= off) x += y;
    }
    int excl = x - tot;
    cur[t] = excl;
    int node = b * 64 + t;
    if (node < n) { row_off[node] = base + excl; row_end[node] = base + excl + tot; }
  }
  __syncthreads();
  for (int i = t; i < c; i += 256) {
    uint2 p = ews[base + i];
    int d = (unsigned)p.x >> 26;
    int pos = base + atomicAdd(&cur[d], 1);
    ews2[pos] = (p.x & 0xFFFFu) | ((unsigned)ftof16(__uint_as_float(p.y)) << 16);
  }
}

// decode + gather + fma for a pair of packed edge records (half selects)
#define SPMM_PAIR(ua, ub)                                                      \
  {                                                                            \
    unsigned u = half ? (ub) : (ua);                                           \
    float wt = f16tof((unsigned short)(u >> 16));                              \
    const uint2 xv = *(const uint2*)(xin + (size_t)(u & 0xFFFFu) * HDIM + fo); \
    acc.x = fmaf(wt, __uint_as_float(xv.x << 16), acc.x);                      \
    acc.y = fmaf(wt, __uint_as_float(xv.x & 0xFFFF0000u), acc.y);              \
    acc.z = fmaf(wt, __uint_as_float(xv.y << 16), acc.z);                      \
    acc.w = fmaf(wt, __uint_as_float(xv.y & 0xFFFF0000u), acc.w);              \
  }

// spmm inner loop for one node -> acc (float4), wave-per-node
#define SPMM_NODE_LOOP(ep, cnt)                                                 \
  int k = 0;                                                                    \
  for (; k + 16 <= cnt; k += 16) {                                              \
    unsigned a0 = ep[k + 0], a1 = ep[k + 1], a2 = ep[k + 2], a3 = ep[k + 3];    \
    unsigned a4 = ep[k + 4], a5 = ep[k + 5], a6 = ep[k + 6], a7 = ep[k + 7];    \
    unsigned a8 = ep[k + 8], a9 = ep[k + 9], a10 = ep[k + 10], a11 = ep[k + 11];\
    unsigned a12 = ep[k + 12], a13 = ep[k + 13], a14 = ep[k + 14],              \
             a15 = ep[k + 15];                                                  \
    SPMM_PAIR(a0, a1); SPMM_PAIR(a2, a3); SPMM_PAIR(a4, a5); SPMM_PAIR(a6, a7); \
    SPMM_PAIR(a8, a9); SPMM_PAIR(a10, a11); SPMM_PAIR(a12, a13);                \
    SPMM_PAIR(a14, a15);                                                        \
  }                                                                             \
  for (; k + 8 <= cnt; k += 8) {                                                \
    unsigned a0 = ep[k + 0], a1 = ep[k + 1], a2 = ep[k + 2], a3 = ep[k + 3];    \
    unsigned a4 = ep[k + 4], a5 = ep[k + 5], a6 = ep[k + 6], a7 = ep[k + 7];    \
    SPMM_PAIR(a0, a1); SPMM_PAIR(a2, a3); SPMM_PAIR(a4, a5); SPMM_PAIR(a6, a7); \
  }                                                                             \
  for (; k < cnt; k += 2) {                                                     \
    unsigned a0 = ep[k];                                                        \
    unsigned a1 = (k + 1 < cnt) ? ep[k + 1] : 0u;                               \
    SPMM_PAIR(a0, a1);                                                          \
  }

// ---- fused spmm1 + gemm2: block = 16 nodes; spmm1 -> LDS bf16 tile -> MFMA @ W2T ----
// C row i of gemm2 depends only on h1 row i, so the handoff is block-local.
// Deletes the gemm2 dispatch and the 25.6MB bufH2 round trip.
__global__ __launch_bounds__(256) void spmm1_gemm2(const unsigned short* __restrict__ xin,
                                                   const unsigned* __restrict__ ews,
                                                   const int* __restrict__ row_off,
                                                   const int* __restrict__ row_end,
                                                   const float* __restrict__ bias,
                                                   const unsigned short* __restrict__ W2T,
                                                   unsigned short* __restrict__ C,
                                                   int n) {
  __shared__ unsigned short As[16][136];
  const int t = threadIdx.x;
  const int l = t & 63;
  const int w = t >> 6;
  const int fo = (l & 31) * 4;
  const int half = l >> 5;
  const int nb0 = blockIdx.x * 16;
  // spmm phase: wave w handles nodes w*4 .. w*4+3 (relu(A h0 + b1) -> LDS)
#pragma unroll
  for (int j = 0; j < 4; ++j) {
    const int node = nb0 + w * 4 + j;
    if (node < n) {
      const int ue0 = __builtin_amdgcn_readfirstlane(row_off[node]);
      const int ue1 = __builtin_amdgcn_readfirstlane(row_end[node]);
      const int cnt = ue1 - ue0;
      const unsigned* ep = ews + ue0;
      float4 acc = make_float4(0.f, 0.f, 0.f, 0.f);
      SPMM_NODE_LOOP(ep, cnt)
      acc.x += __shfl_xor(acc.x, 32, 64);
      acc.y += __shfl_xor(acc.y, 32, 64);
      acc.z += __shfl_xor(acc.z, 32, 64);
      acc.w += __shfl_xor(acc.w, 32, 64);
      if (l < 32) {
        float4 bv = *(const float4*)(bias + fo);
        float r0 = fmaxf(acc.x + bv.x, 0.f), r1 = fmaxf(acc.y + bv.y, 0.f);
        float r2 = fmaxf(acc.z + bv.z, 0.f), r3 = fmaxf(acc.w + bv.w, 0.f);
        *(uint2*)&As[w * 4 + j][fo] = make_uint2(pkbf(r0, r1), pkbf(r2, r3));
      }
    }
  }
  __syncthreads();
  // gemm phase: wave w computes cols [w*32, w*32+32), rows = the block's 16 nodes
  const int ln = l & 15, quad = l >> 4;
  f32x4 acc2[2];
  acc2[0] = (f32x4){0.f, 0.f, 0.f, 0.f};
  acc2[1] = (f32x4){0.f, 0.f, 0.f, 0.f};
#pragma unroll
  for (int k0 = 0; k0 < HDIM; k0 += 32) {
    bf16x8 af = *(const bf16x8*)&As[ln][k0 + quad * 8];
#pragma unroll
    for (int ti = 0; ti < 2; ++ti) {
      bf16x8 bfv = *(const bf16x8*)(W2T + (size_t)(w * 32 + ti * 16 + ln) * HDIM +
                                    k0 + quad * 8);
      acc2[ti] = __builtin_amdgcn_mfma_f32_16x16x32_bf16(af, bfv, acc2[ti], 0, 0, 0);
    }
  }
#pragma unroll
  for (int r = 0; r < 4; ++r) {
    int grow = nb0 + quad * 4 + r;
    if (grow < n) {
#pragma unroll
      for (int ti = 0; ti < 2; ++ti)
        C[(size_t)grow * HDIM + w * 32 + ti * 16 + ln] = bfr(acc2[ti][r]);
    }
  }
}

// ---------------- SPMM v2 (proven): full-width, wave/node, 16-edge unroll ----------------
__global__ __launch_bounds__(256) void spmm_f32(const unsigned short* __restrict__ xin,
                                                const unsigned* __restrict__ ews,
                                                const int* __restrict__ row_off,
                                                const int* __restrict__ row_end,
                                                const float* __restrict__ bias,
                                                float* __restrict__ outp, int n) {
  const int t = threadIdx.x;
  const int l = t & 63;
  const int node = blockIdx.x * 4 + (t >> 6);
  if (node >= n) return;
  const int ue0 = __builtin_amdgcn_readfirstlane(row_off[node]);
  const int ue1 = __builtin_amdgcn_readfirstlane(row_end[node]);
  const int cnt = ue1 - ue0;
  const unsigned* ep = ews + ue0;
  const int fo = (l & 31) * 4;
  const int half = l >> 5;
  float4 acc = make_float4(0.f, 0.f, 0.f, 0.f);
  SPMM_NODE_LOOP(ep, cnt)
  acc.x += __shfl_xor(acc.x, 32, 64);
  acc.y += __shfl_xor(acc.y, 32, 64);
  acc.z += __shfl_xor(acc.z, 32, 64);
  acc.w += __shfl_xor(acc.w, 32, 64);
  if (l < 32) {
    float4 bv = *(const float4*)(bias + fo);
    *(float4*)(outp + (size_t)node * HDIM + fo) =
        make_float4(acc.x + bv.x, acc.y + bv.y, acc.z + bv.z, acc.w + bv.w);
  }
}

// ---------------- head: 256-thread blocks (4 waves share one LDS fill) ----------------
__global__ __launch_bounds__(256) void head_kernel(const float* __restrict__ y,
                                                   const float* __restrict__ h2,
                                                   const float* __restrict__ Wc,
                                                   const float* __restrict__ bc,
                                                   const float* __restrict__ Wf,
                                                   float* __restrict__ out, int n) {
  __shared__ float sW[169 * CCLS];
  const int t = threadIdx.x;
  for (int i = t; i < 400; i += 256) ((float4*)sW)[i] = ((const float4*)Wc)[i];
  for (int i = t; i < 1280; i += 256)
    ((float4*)(sW + CCLS * CCLS))[i] = ((const float4*)(Wf + HDIM * CCLS))[i];
  if (t < 10) ((float4*)(sW + 168 * CCLS))[t] = ((const float4*)bc)[t];
  __syncthreads();

  const int node = blockIdx.x * 256 + t;
  const int nc = node < n ? node : n - 1;
  const float* zy = y + (size_t)nc * CCLS;
  const float* zh = h2 + (size_t)nc * HDIM;

  float acc[40];
#pragma unroll
  for (int cq = 0; cq < 10; ++cq) {
    float4 b4 = *(const float4*)&sW[168 * CCLS + cq * 4];
    acc[cq * 4 + 0] = b4.x; acc[cq * 4 + 1] = b4.y;
    acc[cq * 4 + 2] = b4.z; acc[cq * 4 + 3] = b4.w;
  }

#pragma unroll 2
  for (int kc = 0; kc < 10; ++kc) {      // y part: K = 40
    float4 zv = *(const float4*)(zy + kc * 4);
    float zj[4] = {zv.x, zv.y, zv.z, zv.w};
#pragma unroll
    for (int j = 0; j < 4; ++j) {
      const float* wr = sW + (kc * 4 + j) * CCLS;
#pragma unroll
      for (int cq = 0; cq < 10; ++cq) {
        float4 w4 = *(const float4*)(wr + cq * 4);
        acc[cq * 4 + 0] = fmaf(zj[j], w4.x, acc[cq * 4 + 0]);
        acc[cq * 4 + 1] = fmaf(zj[j], w4.y, acc[cq * 4 + 1]);
        acc[cq * 4 + 2] = fmaf(zj[j], w4.z, acc[cq * 4 + 2]);
        acc[cq * 4 + 3] = fmaf(zj[j], w4.w, acc[cq * 4 + 3]);
      }
    }
  }
#pragma unroll 2
  for (int kc = 0; kc < 32; ++kc) {      // h2 part: K = 128
    float4 zv = *(const float4*)(zh + kc * 4);
    float zj[4] = {zv.x, zv.y, zv.z, zv.w};
#pragma unroll
    for (int j = 0; j < 4; ++j) {
      const float* wr = sW + (40 + kc * 4 + j) * CCLS;
#pragma unroll
      for (int cq = 0; cq < 10; ++cq) {
        float4 w4 = *(const float4*)(wr + cq * 4);
        acc[cq * 4 + 0] = fmaf(zj[j], w4.x, acc[cq * 4 + 0]);
        acc[cq * 4 + 1] = fmaf(zj[j], w4.y, acc[cq * 4 + 1]);
        acc[cq * 4 + 2] = fmaf(zj[j], w4.z, acc[cq * 4 + 2]);
        acc[cq * 4 + 3] = fmaf(zj[j], w4.w, acc[cq * 4 + 3]);
      }
    }
  }

  // in-register softmax over 40 logits
  float m = acc[0];
#pragma unroll
  for (int c = 1; c < 40; ++c) m = fmaxf(m, acc[c]);
  float sum = 0.f;
#pragma unroll
  for (int c = 0; c < 40; ++c) { acc[c] = __expf(acc[c] - m); sum += acc[c]; }
  float inv = 1.0f / sum;
  if (node < n) {
    float* op = out + (size_t)node * CCLS;
#pragma unroll
    for (int cq = 0; cq < 10; ++cq) {
      float4 o = make_float4(acc[cq * 4 + 0] * inv, acc[cq * 4 + 1] * inv,
                             acc[cq * 4 + 2] * inv, acc[cq * 4 + 3] * inv);
      *(float4*)(op + cq * 4) = o;
    }
  }
}

extern "C" void kernel_launch(void* const* d_in, const int* in_sizes, int n_in,
                              void* d_out, int out_size, void* d_ws, size_t ws_size,
                              hipStream_t stream) {
  (void)n_in; (void)out_size; (void)ws_size;
  const float* features = (const float*)d_in[0];
  const int*   src      = (const int*)d_in[1];
  const int*   dst      = (const int*)d_in[2];
  const float* ew       = (const float*)d_in[3];
  const float* y        = (const float*)d_in[4];
  const float* W1       = (const float*)d_in[5];
  const float* b1       = (const float*)d_in[6];
  const float* W2       = (const float*)d_in[7];
  const float* b2       = (const float*)d_in[8];
  const float* We       = (const float*)d_in[9];
  const float* be       = (const float*)d_in[10];
  const float* Wf       = (const float*)d_in[11];
  const float* bf       = (const float*)d_in[12];
  float* out = (float*)d_out;

  const int n = in_sizes[0] / F_IN;   // 50000
  const int e = in_sizes[1];          // 1600000
  const int nb = (n + 63) >> 6;       // 782 buckets

  char* w = (char*)d_ws;
  auto take = [&](size_t bytes) {
    char* p = w;
    w += (bytes + 255) & ~(size_t)255;
    return p;
  };
  int*   gcursor  = (int*)take((size_t)nb * 4);
  int*   row_off  = (int*)take((size_t)n * 4);
  int*   row_end  = (int*)take((size_t)n * 4);
  uint2* ews      = (uint2*)take((size_t)nb * CAP * 8);
  unsigned* ews2  = (unsigned*)take((size_t)nb * CAP * 4);
  unsigned short* bufH1  = (unsigned short*)take((size_t)n * HDIM * 2);  // x@W1
  unsigned short* bufH2  = (unsigned short*)take((size_t)n * HDIM * 2);  // h1@W2
  float* bufS     = (float*)take((size_t)n * HDIM * 4);
  unsigned short* W1T = (unsigned short*)take((size_t)HDIM * F_IN * 2);
  unsigned short* W2T = (unsigned short*)take((size_t)HDIM * HDIM * 2);
  float* Wc       = (float*)take(CCLS * CCLS * 4);
  float* bc       = (float*)take(CCLS * 4);

  const int nsb = (e + EPB - 1) / EPB;               // 196 scatter blocks
  const int ngb = (n + 15) / 16;                     // 3125 gemm1 blocks (16-row tiles)

  prep_kernel<<<129, 256, 0, stream>>>(W1, W1T, gcursor, nb);
  scatter_gemm1<<<nsb + ngb + 64 + 2, 256, 0, stream>>>(
      src, dst, ew, gcursor, ews, features, W1T, bufH1,
      W2, W2T, We, be, Wf, bf, Wc, bc, e, nb, nsb, ngb, n);
  bucket_sort<<<nb, 256, 0, stream>>>(ews, gcursor, ews2, row_off, row_end, n, nb);

  spmm1_gemm2<<<(n + 15) / 16, 256, 0, stream>>>(bufH1, ews2, row_off, row_end, b1,
                                                 W2T, bufH2, n);
  spmm_f32<<<(n + 3) / 4, 256, 0, stream>>>(bufH2, ews2, row_off, row_end, b2, bufS, n);
  head_kernel<<<(n + 255) / 256, 256, 0, stream>>>(y, bufS, Wc, bc, Wf, out, n);
}